// Round 1
// baseline (2160.346 us; speedup 1.0000x reference)
//
#include <hip/hip_runtime.h>

#define C_   128
#define A_   4
#define S_   16
#define RH_  64
#define H_   8
#define AH_  256
#define OUT_ 128

__device__ __forceinline__ float sigf(float x) { return 1.0f / (1.0f + __expf(-x)); }

// monotone float <-> uint mapping for atomicMax-based segment max
__device__ __forceinline__ unsigned enc(float x) {
    unsigned b = __float_as_uint(x);
    return (b & 0x80000000u) ? ~b : (b | 0x80000000u);
}
__device__ __forceinline__ float dec(unsigned u) {
    unsigned b = (u & 0x80000000u) ? (u & 0x7fffffffu) : ~u;
    return __uint_as_float(b);
}

// K1: radial MLP (silu(es@w1+b1) @ w2 + b2) -> dtp with edge_attr -> msg = message * tp
__global__ __launch_bounds__(256) void k_msg(
    const float* __restrict__ message, const float* __restrict__ edge_attr,
    const float* __restrict__ edge_scalars,
    const float* __restrict__ w_rad1, const float* __restrict__ b_rad1,
    const float* __restrict__ w_rad2, const float* __restrict__ b_rad2,
    float* __restrict__ msg)
{
    __shared__ float w1_s[S_][RH_];   // 4KB
    __shared__ float es_s[32][20];    // padded (bank spread)
    __shared__ float attr_s[32][4];
    __shared__ float h_s[32][68];     // padded, float4-aligned
    const int t = threadIdx.x;
    const long e0 = (long)blockIdx.x * 32;

    *(float4*)&((float*)w1_s)[t * 4] = *(const float4*)&w_rad1[t * 4];
    if (t < 128) {
        int el = t >> 2, s4 = (t & 3) * 4;
        *(float4*)&es_s[el][s4] = *(const float4*)&edge_scalars[(e0 + el) * S_ + s4];
    }
    if (t < 32) *(float4*)&attr_s[t][0] = *(const float4*)&edge_attr[(e0 + t) * A_];
    __syncthreads();

    {   // h = silu(es @ w_rad1 + b_rad1): 32 edges x 64, 8 per thread
        const int el = t >> 3, r0 = (t & 7) * 8;
        float acc[8];
        #pragma unroll
        for (int i = 0; i < 8; i++) acc[i] = b_rad1[r0 + i];
        #pragma unroll
        for (int s = 0; s < S_; s++) {
            const float ev = es_s[el][s];
            #pragma unroll
            for (int i = 0; i < 8; i++) acc[i] += ev * w1_s[s][r0 + i];
        }
        #pragma unroll
        for (int i = 0; i < 8; i++) { float x = acc[i]; h_s[el][r0 + i] = x * sigf(x); }
    }
    __syncthreads();

    // wfull[el][4c+a] = b_rad2 + h[el] . w_rad2[:,4c+a]; msg = message * (wfull . attr)
    const int c  = t & 127;
    const int eh = t >> 7;   // 0/1 -> 16 edges each
    float4 acc4[16];
    {
        const float4 b2 = *(const float4*)&b_rad2[c * 4];
        #pragma unroll
        for (int i = 0; i < 16; i++) acc4[i] = b2;
    }
    const float* wp = w_rad2 + c * 4;
    for (int r4 = 0; r4 < 16; r4++) {
        const float4 w0 = *(const float4*)&wp[(r4 * 4 + 0) * 512];
        const float4 w1 = *(const float4*)&wp[(r4 * 4 + 1) * 512];
        const float4 w2 = *(const float4*)&wp[(r4 * 4 + 2) * 512];
        const float4 w3 = *(const float4*)&wp[(r4 * 4 + 3) * 512];
        #pragma unroll
        for (int i = 0; i < 16; i++) {
            const float4 hv = *(const float4*)&h_s[eh * 16 + i][r4 * 4];
            acc4[i].x += hv.x * w0.x + hv.y * w1.x + hv.z * w2.x + hv.w * w3.x;
            acc4[i].y += hv.x * w0.y + hv.y * w1.y + hv.z * w2.y + hv.w * w3.y;
            acc4[i].z += hv.x * w0.z + hv.y * w1.z + hv.z * w2.z + hv.w * w3.z;
            acc4[i].w += hv.x * w0.w + hv.y * w1.w + hv.z * w2.w + hv.w * w3.w;
        }
    }
    #pragma unroll
    for (int i = 0; i < 16; i++) {
        const int el = eh * 16 + i;
        const float4 a4 = *(const float4*)&attr_s[el][0];
        const float d = acc4[i].x * a4.x + acc4[i].y * a4.y + acc4[i].z * a4.z + acc4[i].w * a4.w;
        const long e = e0 + el;
        msg[e * C_ + c] = message[e * C_ + c] * d;
    }
}

// K2: alpha = SLR(msg @ w_alpha + b_alpha); logit[e,h] = sum_k alpha*alpha_dot; atomicMax amax
__global__ __launch_bounds__(256) void k_alpha(
    const float* __restrict__ msg,
    const float* __restrict__ w_alpha, const float* __restrict__ b_alpha,
    const float* __restrict__ alpha_dot, const int* __restrict__ edge_dst,
    float* __restrict__ logits, unsigned* __restrict__ amax_u)
{
    __shared__ float msg_s[32][C_];   // 16KB
    const int t = threadIdx.x;
    const long e0 = (long)blockIdx.x * 32;
    #pragma unroll
    for (int i = 0; i < 4; i++) {
        const int idx = t + i * 256;
        const int el = idx >> 5, c4 = (idx & 31) * 4;
        *(float4*)&msg_s[el][c4] = *(const float4*)&msg[(e0 + el) * C_ + c4];
    }
    __syncthreads();

    const int j0 = (t & 63) * 4;   // 4 of 256 alpha channels
    const int g  = t >> 6;         // wave id -> 8 edges
    float4 acc4[8];
    {
        const float4 b = *(const float4*)&b_alpha[j0];
        #pragma unroll
        for (int i = 0; i < 8; i++) acc4[i] = b;
    }
    const float* wp = w_alpha + j0;
    for (int c4 = 0; c4 < 32; c4++) {
        const float4 w0 = *(const float4*)&wp[(c4 * 4 + 0) * AH_];
        const float4 w1 = *(const float4*)&wp[(c4 * 4 + 1) * AH_];
        const float4 w2 = *(const float4*)&wp[(c4 * 4 + 2) * AH_];
        const float4 w3 = *(const float4*)&wp[(c4 * 4 + 3) * AH_];
        #pragma unroll
        for (int i = 0; i < 8; i++) {
            const float4 mv = *(const float4*)&msg_s[g * 8 + i][c4 * 4];
            acc4[i].x += mv.x * w0.x + mv.y * w1.x + mv.z * w2.x + mv.w * w3.x;
            acc4[i].y += mv.x * w0.y + mv.y * w1.y + mv.z * w2.y + mv.w * w3.y;
            acc4[i].z += mv.x * w0.z + mv.y * w1.z + mv.z * w2.z + mv.w * w3.z;
            acc4[i].w += mv.x * w0.w + mv.y * w1.w + mv.z * w2.w + mv.w * w3.w;
        }
    }
    const float4 ad = *(const float4*)&alpha_dot[j0];
    const int h = j0 >> 5;
    #pragma unroll
    for (int i = 0; i < 8; i++) {
        const float4 a = acc4[i];
        const float y0 = 0.5f * (1.2f * a.x + 0.8f * a.x * (2.0f * sigf(a.x) - 1.0f));
        const float y1 = 0.5f * (1.2f * a.y + 0.8f * a.y * (2.0f * sigf(a.y) - 1.0f));
        const float y2 = 0.5f * (1.2f * a.z + 0.8f * a.z * (2.0f * sigf(a.z) - 1.0f));
        const float y3 = 0.5f * (1.2f * a.w + 0.8f * a.w * (2.0f * sigf(a.w) - 1.0f));
        float v = y0 * ad.x + y1 * ad.y + y2 * ad.z + y3 * ad.w;
        v += __shfl_xor(v, 1);
        v += __shfl_xor(v, 2);
        v += __shfl_xor(v, 4);   // 8-lane group = one head (8 lanes x 4 k = 32)
        if ((t & 7) == 0) {
            const long e = e0 + g * 8 + i;
            logits[e * H_ + h] = v;
            const int n = edge_dst[e];
            atomicMax(&amax_u[n * H_ + h], enc(v));
        }
    }
}

// K3: denom[n,h] += exp(logit - amax)
__global__ __launch_bounds__(256) void k_denom(
    const float* __restrict__ logits, const int* __restrict__ edge_dst,
    const unsigned* __restrict__ amax_u, float* __restrict__ denom, int EH)
{
    const int t = blockIdx.x * 256 + threadIdx.x;
    if (t >= EH) return;
    const int e = t >> 3, h = t & 7;
    const int n = edge_dst[e];
    const float am = dec(amax_u[n * H_ + h]);
    atomicAdd(&denom[n * H_ + h], __expf(logits[t] - am));
}

// K4: value = silu(msg@w_lin_act+b)*dtp_v(attr); v2 = value@w_lin_v+b; node += v2 * softmax_w
__global__ __launch_bounds__(256) void k_value(
    const float* __restrict__ msg, const float* __restrict__ edge_attr,
    const float* __restrict__ w_lin_act, const float* __restrict__ b_lin_act,
    const float* __restrict__ w_dtp_v,
    const float* __restrict__ w_lin_v, const float* __restrict__ b_lin_v,
    const float* __restrict__ logits, const int* __restrict__ edge_dst,
    const unsigned* __restrict__ amax_u, const float* __restrict__ denom,
    float* __restrict__ node)
{
    __shared__ float msg_s[32][C_];
    __shared__ float val_s[32][C_];
    __shared__ float attr_s[32][4];
    __shared__ float wgt_s[32][H_];
    __shared__ int   dst_s[32];
    const int t = threadIdx.x;
    const long e0 = (long)blockIdx.x * 32;
    #pragma unroll
    for (int i = 0; i < 4; i++) {
        const int idx = t + i * 256;
        const int el = idx >> 5, c4 = (idx & 31) * 4;
        *(float4*)&msg_s[el][c4] = *(const float4*)&msg[(e0 + el) * C_ + c4];
    }
    if (t < 32) {
        *(float4*)&attr_s[t][0] = *(const float4*)&edge_attr[(e0 + t) * A_];
        dst_s[t] = edge_dst[e0 + t];
    }
    __syncthreads();
    {   // softmax weights, one (el,h) per thread
        const int el = t >> 3, h = t & 7;
        const long e = e0 + el;
        const int n = dst_s[el];
        const float am = dec(amax_u[n * H_ + h]);
        const float d  = denom[n * H_ + h];
        wgt_s[el][h] = __expf(logits[e * H_ + h] - am) / (d + 1e-16f);
    }
    {   // phase 1: gate GEMM, 8 edges x 2 cols per thread
        const int c2 = t & 63;
        const int g  = t >> 6;
        float2 acc[8];
        const float ba = b_lin_act[c2], bb = b_lin_act[c2 + 64];
        #pragma unroll
        for (int i = 0; i < 8; i++) { acc[i].x = ba; acc[i].y = bb; }
        const float* wp = w_lin_act + c2;
        for (int c4 = 0; c4 < 32; c4++) {
            const float wa0 = wp[(c4*4+0)*C_], wb0 = wp[(c4*4+0)*C_ + 64];
            const float wa1 = wp[(c4*4+1)*C_], wb1 = wp[(c4*4+1)*C_ + 64];
            const float wa2 = wp[(c4*4+2)*C_], wb2 = wp[(c4*4+2)*C_ + 64];
            const float wa3 = wp[(c4*4+3)*C_], wb3 = wp[(c4*4+3)*C_ + 64];
            #pragma unroll
            for (int i = 0; i < 8; i++) {
                const float4 mv = *(const float4*)&msg_s[g * 8 + i][c4 * 4];
                acc[i].x += mv.x * wa0 + mv.y * wa1 + mv.z * wa2 + mv.w * wa3;
                acc[i].y += mv.x * wb0 + mv.y * wb1 + mv.z * wb2 + mv.w * wb3;
            }
        }
        const float4 wdva = *(const float4*)&w_dtp_v[c2 * 4];
        const float4 wdvb = *(const float4*)&w_dtp_v[(c2 + 64) * 4];
        #pragma unroll
        for (int i = 0; i < 8; i++) {
            const int el = g * 8 + i;
            const float4 a4 = *(const float4*)&attr_s[el][0];
            const float dva = wdva.x*a4.x + wdva.y*a4.y + wdva.z*a4.z + wdva.w*a4.w;
            const float dvb = wdvb.x*a4.x + wdvb.y*a4.y + wdvb.z*a4.z + wdvb.w*a4.w;
            const float xa = acc[i].x, xb = acc[i].y;
            val_s[el][c2]      = xa * sigf(xa) * dva;
            val_s[el][c2 + 64] = xb * sigf(xb) * dvb;
        }
    }
    __syncthreads();
    {   // phase 2: value GEMM + weighted scatter
        const int j0 = (t & 63) * 4;
        const int g  = t >> 6;
        float4 acc4[8];
        const float4 b = *(const float4*)&b_lin_v[j0];
        #pragma unroll
        for (int i = 0; i < 8; i++) acc4[i] = b;
        const float* wp = w_lin_v + j0;
        for (int c4 = 0; c4 < 32; c4++) {
            const float4 w0 = *(const float4*)&wp[(c4 * 4 + 0) * AH_];
            const float4 w1 = *(const float4*)&wp[(c4 * 4 + 1) * AH_];
            const float4 w2 = *(const float4*)&wp[(c4 * 4 + 2) * AH_];
            const float4 w3 = *(const float4*)&wp[(c4 * 4 + 3) * AH_];
            #pragma unroll
            for (int i = 0; i < 8; i++) {
                const float4 vv = *(const float4*)&val_s[g * 8 + i][c4 * 4];
                acc4[i].x += vv.x * w0.x + vv.y * w1.x + vv.z * w2.x + vv.w * w3.x;
                acc4[i].y += vv.x * w0.y + vv.y * w1.y + vv.z * w2.y + vv.w * w3.y;
                acc4[i].z += vv.x * w0.z + vv.y * w1.z + vv.z * w2.z + vv.w * w3.z;
                acc4[i].w += vv.x * w0.w + vv.y * w1.w + vv.z * w2.w + vv.w * w3.w;
            }
        }
        const int h = j0 >> 5;
        #pragma unroll
        for (int i = 0; i < 8; i++) {
            const int el = g * 8 + i;
            const float w = wgt_s[el][h];
            float* np = node + (long)dst_s[el] * AH_ + j0;
            atomicAdd(np + 0, acc4[i].x * w);
            atomicAdd(np + 1, acc4[i].y * w);
            atomicAdd(np + 2, acc4[i].z * w);
            atomicAdd(np + 3, acc4[i].w * w);
        }
    }
}

// K5: out = node @ w_proj + b_proj
__global__ __launch_bounds__(256) void k_proj(
    const float* __restrict__ node, const float* __restrict__ w_proj,
    const float* __restrict__ b_proj, float* __restrict__ out)
{
    __shared__ float node_s[32][AH_];   // 32KB
    const int t = threadIdx.x;
    const long n0 = (long)blockIdx.x * 32;
    #pragma unroll
    for (int i = 0; i < 8; i++) {
        const int idx = t + i * 256;
        const int nl = idx >> 6, c4 = (idx & 63) * 4;
        *(float4*)&node_s[nl][c4] = *(const float4*)&node[(n0 + nl) * AH_ + c4];
    }
    __syncthreads();
    const int j0 = (t & 31) * 4;
    const int g  = t >> 5;     // 8 groups x 4 nodes
    float4 acc4[4];
    const float4 b = *(const float4*)&b_proj[j0];
    #pragma unroll
    for (int i = 0; i < 4; i++) acc4[i] = b;
    const float* wp = w_proj + j0;
    for (int c4 = 0; c4 < 64; c4++) {
        const float4 w0 = *(const float4*)&wp[(c4 * 4 + 0) * OUT_];
        const float4 w1 = *(const float4*)&wp[(c4 * 4 + 1) * OUT_];
        const float4 w2 = *(const float4*)&wp[(c4 * 4 + 2) * OUT_];
        const float4 w3 = *(const float4*)&wp[(c4 * 4 + 3) * OUT_];
        #pragma unroll
        for (int i = 0; i < 4; i++) {
            const float4 nv = *(const float4*)&node_s[g * 4 + i][c4 * 4];
            acc4[i].x += nv.x * w0.x + nv.y * w1.x + nv.z * w2.x + nv.w * w3.x;
            acc4[i].y += nv.x * w0.y + nv.y * w1.y + nv.z * w2.y + nv.w * w3.y;
            acc4[i].z += nv.x * w0.z + nv.y * w1.z + nv.z * w2.z + nv.w * w3.z;
            acc4[i].w += nv.x * w0.w + nv.y * w1.w + nv.z * w2.w + nv.w * w3.w;
        }
    }
    #pragma unroll
    for (int i = 0; i < 4; i++) {
        const long n = n0 + g * 4 + i;
        *(float4*)&out[n * OUT_ + j0] = acc4[i];
    }
}

extern "C" void kernel_launch(void* const* d_in, const int* in_sizes, int n_in,
                              void* d_out, int out_size, void* d_ws, size_t ws_size,
                              hipStream_t stream)
{
    const float* message      = (const float*)d_in[0];
    const float* edge_attr    = (const float*)d_in[1];
    const float* edge_scalars = (const float*)d_in[2];
    const float* w_rad1       = (const float*)d_in[3];
    const float* b_rad1       = (const float*)d_in[4];
    const float* w_rad2       = (const float*)d_in[5];
    const float* b_rad2       = (const float*)d_in[6];
    const float* w_dtp_v      = (const float*)d_in[7];
    const float* w_lin_act    = (const float*)d_in[8];
    const float* b_lin_act    = (const float*)d_in[9];
    const float* w_alpha      = (const float*)d_in[10];
    const float* b_alpha      = (const float*)d_in[11];
    const float* w_lin_v      = (const float*)d_in[12];
    const float* b_lin_v      = (const float*)d_in[13];
    const float* alpha_dot    = (const float*)d_in[14];
    const float* w_proj       = (const float*)d_in[15];
    const float* b_proj       = (const float*)d_in[16];
    const int*   edge_dst     = (const int*)d_in[17];

    const int E = in_sizes[0] / C_;
    const int N = out_size / OUT_;

    // workspace layout: [node N*256][amax N*8][denom N*8][msg E*128][logits E*8]
    char* ws = (char*)d_ws;
    float*    node   = (float*)ws;
    unsigned* amax_u = (unsigned*)(ws + (size_t)N * AH_ * 4);
    float*    denom  = (float*)(ws + (size_t)N * (AH_ + H_) * 4);
    float*    msg    = (float*)(ws + (size_t)N * (AH_ + 2 * H_) * 4);
    float*    logits = (float*)(ws + (size_t)N * (AH_ + 2 * H_) * 4 + (size_t)E * C_ * 4);

    // zero node accumulator + amax (encoded: 0 < any finite) + denom in one shot
    hipMemsetAsync(d_ws, 0, (size_t)N * (AH_ + 2 * H_) * 4, stream);

    const int nbE = E / 32;
    k_msg  <<<nbE, 256, 0, stream>>>(message, edge_attr, edge_scalars,
                                     w_rad1, b_rad1, w_rad2, b_rad2, msg);
    k_alpha<<<nbE, 256, 0, stream>>>(msg, w_alpha, b_alpha, alpha_dot, edge_dst,
                                     logits, amax_u);
    k_denom<<<(E * H_ + 255) / 256, 256, 0, stream>>>(logits, edge_dst, amax_u, denom, E * H_);
    k_value<<<nbE, 256, 0, stream>>>(msg, edge_attr, w_lin_act, b_lin_act, w_dtp_v,
                                     w_lin_v, b_lin_v, logits, edge_dst, amax_u, denom, node);
    k_proj <<<N / 32, 256, 0, stream>>>(node, w_proj, b_proj, (float*)d_out);
}

// Round 2
// 1571.727 us; speedup vs baseline: 1.3745x; 1.3745x over previous
//
#include <hip/hip_runtime.h>

#define C_   128
#define A_   4
#define S_   16
#define RH_  64
#define H_   8
#define AH_  256
#define OUT_ 128

__device__ __forceinline__ float sigf(float x) { return 1.0f / (1.0f + __expf(-x)); }

// monotone float <-> uint mapping for atomicMax-based segment max
__device__ __forceinline__ unsigned enc(float x) {
    unsigned b = __float_as_uint(x);
    return (b & 0x80000000u) ? ~b : (b | 0x80000000u);
}
__device__ __forceinline__ float dec(unsigned u) {
    unsigned b = (u & 0x80000000u) ? (u & 0x7fffffffu) : ~u;
    return __uint_as_float(b);
}

// K1: radial MLP (silu(es@w1+b1) @ w2 + b2) -> dtp with edge_attr -> msg = message * tp
__global__ __launch_bounds__(256) void k_msg(
    const float* __restrict__ message, const float* __restrict__ edge_attr,
    const float* __restrict__ edge_scalars,
    const float* __restrict__ w_rad1, const float* __restrict__ b_rad1,
    const float* __restrict__ w_rad2, const float* __restrict__ b_rad2,
    float* __restrict__ msg)
{
    __shared__ float w1_s[S_][RH_];   // 4KB
    __shared__ float es_s[32][20];    // padded (bank spread)
    __shared__ float attr_s[32][4];
    __shared__ float h_s[32][68];     // padded, float4-aligned
    const int t = threadIdx.x;
    const long e0 = (long)blockIdx.x * 32;

    *(float4*)&((float*)w1_s)[t * 4] = *(const float4*)&w_rad1[t * 4];
    if (t < 128) {
        int el = t >> 2, s4 = (t & 3) * 4;
        *(float4*)&es_s[el][s4] = *(const float4*)&edge_scalars[(e0 + el) * S_ + s4];
    }
    if (t < 32) *(float4*)&attr_s[t][0] = *(const float4*)&edge_attr[(e0 + t) * A_];
    __syncthreads();

    {   // h = silu(es @ w_rad1 + b_rad1): 32 edges x 64, 8 per thread
        const int el = t >> 3, r0 = (t & 7) * 8;
        float acc[8];
        #pragma unroll
        for (int i = 0; i < 8; i++) acc[i] = b_rad1[r0 + i];
        #pragma unroll
        for (int s = 0; s < S_; s++) {
            const float ev = es_s[el][s];
            #pragma unroll
            for (int i = 0; i < 8; i++) acc[i] += ev * w1_s[s][r0 + i];
        }
        #pragma unroll
        for (int i = 0; i < 8; i++) { float x = acc[i]; h_s[el][r0 + i] = x * sigf(x); }
    }
    __syncthreads();

    // wfull[el][4c+a] = b_rad2 + h[el] . w_rad2[:,4c+a]; msg = message * (wfull . attr)
    const int c  = t & 127;
    const int eh = t >> 7;   // 0/1 -> 16 edges each
    float4 acc4[16];
    {
        const float4 b2 = *(const float4*)&b_rad2[c * 4];
        #pragma unroll
        for (int i = 0; i < 16; i++) acc4[i] = b2;
    }
    const float* wp = w_rad2 + c * 4;
    for (int r4 = 0; r4 < 16; r4++) {
        const float4 w0 = *(const float4*)&wp[(r4 * 4 + 0) * 512];
        const float4 w1 = *(const float4*)&wp[(r4 * 4 + 1) * 512];
        const float4 w2 = *(const float4*)&wp[(r4 * 4 + 2) * 512];
        const float4 w3 = *(const float4*)&wp[(r4 * 4 + 3) * 512];
        #pragma unroll
        for (int i = 0; i < 16; i++) {
            const float4 hv = *(const float4*)&h_s[eh * 16 + i][r4 * 4];
            acc4[i].x += hv.x * w0.x + hv.y * w1.x + hv.z * w2.x + hv.w * w3.x;
            acc4[i].y += hv.x * w0.y + hv.y * w1.y + hv.z * w2.y + hv.w * w3.y;
            acc4[i].z += hv.x * w0.z + hv.y * w1.z + hv.z * w2.z + hv.w * w3.z;
            acc4[i].w += hv.x * w0.w + hv.y * w1.w + hv.z * w2.w + hv.w * w3.w;
        }
    }
    #pragma unroll
    for (int i = 0; i < 16; i++) {
        const int el = eh * 16 + i;
        const float4 a4 = *(const float4*)&attr_s[el][0];
        const float d = acc4[i].x * a4.x + acc4[i].y * a4.y + acc4[i].z * a4.z + acc4[i].w * a4.w;
        const long e = e0 + el;
        msg[e * C_ + c] = message[e * C_ + c] * d;
    }
}

// K2: alpha = SLR(msg @ w_alpha + b_alpha); logit[e,h] = sum_k alpha*alpha_dot; atomicMax amax
__global__ __launch_bounds__(256) void k_alpha(
    const float* __restrict__ msg,
    const float* __restrict__ w_alpha, const float* __restrict__ b_alpha,
    const float* __restrict__ alpha_dot, const int* __restrict__ edge_dst,
    float* __restrict__ logits, unsigned* __restrict__ amax_u)
{
    __shared__ float msg_s[32][C_];   // 16KB
    const int t = threadIdx.x;
    const long e0 = (long)blockIdx.x * 32;
    #pragma unroll
    for (int i = 0; i < 4; i++) {
        const int idx = t + i * 256;
        const int el = idx >> 5, c4 = (idx & 31) * 4;
        *(float4*)&msg_s[el][c4] = *(const float4*)&msg[(e0 + el) * C_ + c4];
    }
    __syncthreads();

    const int j0 = (t & 63) * 4;   // 4 of 256 alpha channels
    const int g  = t >> 6;         // wave id -> 8 edges
    float4 acc4[8];
    {
        const float4 b = *(const float4*)&b_alpha[j0];
        #pragma unroll
        for (int i = 0; i < 8; i++) acc4[i] = b;
    }
    const float* wp = w_alpha + j0;
    for (int c4 = 0; c4 < 32; c4++) {
        const float4 w0 = *(const float4*)&wp[(c4 * 4 + 0) * AH_];
        const float4 w1 = *(const float4*)&wp[(c4 * 4 + 1) * AH_];
        const float4 w2 = *(const float4*)&wp[(c4 * 4 + 2) * AH_];
        const float4 w3 = *(const float4*)&wp[(c4 * 4 + 3) * AH_];
        #pragma unroll
        for (int i = 0; i < 8; i++) {
            const float4 mv = *(const float4*)&msg_s[g * 8 + i][c4 * 4];
            acc4[i].x += mv.x * w0.x + mv.y * w1.x + mv.z * w2.x + mv.w * w3.x;
            acc4[i].y += mv.x * w0.y + mv.y * w1.y + mv.z * w2.y + mv.w * w3.y;
            acc4[i].z += mv.x * w0.z + mv.y * w1.z + mv.z * w2.z + mv.w * w3.z;
            acc4[i].w += mv.x * w0.w + mv.y * w1.w + mv.z * w2.w + mv.w * w3.w;
        }
    }
    const float4 ad = *(const float4*)&alpha_dot[j0];
    const int h = j0 >> 5;
    #pragma unroll
    for (int i = 0; i < 8; i++) {
        const float4 a = acc4[i];
        const float y0 = 0.5f * (1.2f * a.x + 0.8f * a.x * (2.0f * sigf(a.x) - 1.0f));
        const float y1 = 0.5f * (1.2f * a.y + 0.8f * a.y * (2.0f * sigf(a.y) - 1.0f));
        const float y2 = 0.5f * (1.2f * a.z + 0.8f * a.z * (2.0f * sigf(a.z) - 1.0f));
        const float y3 = 0.5f * (1.2f * a.w + 0.8f * a.w * (2.0f * sigf(a.w) - 1.0f));
        float v = y0 * ad.x + y1 * ad.y + y2 * ad.z + y3 * ad.w;
        v += __shfl_xor(v, 1);
        v += __shfl_xor(v, 2);
        v += __shfl_xor(v, 4);   // 8-lane group = one head (8 lanes x 4 k = 32)
        if ((t & 7) == 0) {
            const long e = e0 + g * 8 + i;
            logits[e * H_ + h] = v;
            const int n = edge_dst[e];
            atomicMax(&amax_u[n * H_ + h], enc(v));
        }
    }
}

// K3: denom[n,h] += exp(logit - amax)
__global__ __launch_bounds__(256) void k_denom(
    const float* __restrict__ logits, const int* __restrict__ edge_dst,
    const unsigned* __restrict__ amax_u, float* __restrict__ denom, int EH)
{
    const int t = blockIdx.x * 256 + threadIdx.x;
    if (t >= EH) return;
    const int e = t >> 3, h = t & 7;
    const int n = edge_dst[e];
    const float am = dec(amax_u[n * H_ + h]);
    atomicAdd(&denom[n * H_ + h], __expf(logits[t] - am));
}

// CSR build: histogram, scan, fill
__global__ __launch_bounds__(256) void k_hist(
    const int* __restrict__ edge_dst, int* __restrict__ deg, int E)
{
    const int e = blockIdx.x * 256 + threadIdx.x;
    if (e < E) atomicAdd(&deg[edge_dst[e]], 1);
}

__global__ __launch_bounds__(1024) void k_scan(
    const int* __restrict__ deg, int* __restrict__ base, int* __restrict__ cursor, int N)
{
    __shared__ int part[1024];
    const int t = threadIdx.x;
    const int per = (N + 1023) / 1024;
    const int i0 = t * per;
    int s = 0;
    for (int i = 0; i < per; i++) { int idx = i0 + i; if (idx < N) s += deg[idx]; }
    part[t] = s;
    __syncthreads();
    for (int off = 1; off < 1024; off <<= 1) {
        int v = (t >= off) ? part[t - off] : 0;
        __syncthreads();
        part[t] += v;
        __syncthreads();
    }
    int excl = (t == 0) ? 0 : part[t - 1];
    for (int i = 0; i < per; i++) {
        int idx = i0 + i;
        if (idx < N) { base[idx] = excl; cursor[idx] = excl; excl += deg[idx]; }
    }
}

__global__ __launch_bounds__(256) void k_fill(
    const int* __restrict__ edge_dst, int* __restrict__ cursor,
    int* __restrict__ sorted, int E)
{
    const int e = blockIdx.x * 256 + threadIdx.x;
    if (e < E) {
        const int pos = atomicAdd(&cursor[edge_dst[e]], 1);
        sorted[pos] = e;
    }
}

// K4: processes edges in dst-sorted order. value GEMMs as before, then in-LDS
// run-length reduction by dst: interior nodes -> plain store, boundary -> atomicAdd.
__global__ __launch_bounds__(256) void k_value(
    const float* __restrict__ msg, const float* __restrict__ edge_attr,
    const float* __restrict__ w_lin_act, const float* __restrict__ b_lin_act,
    const float* __restrict__ w_dtp_v,
    const float* __restrict__ w_lin_v, const float* __restrict__ b_lin_v,
    const float* __restrict__ logits, const int* __restrict__ edge_dst,
    const unsigned* __restrict__ amax_u, const float* __restrict__ denom,
    const int* __restrict__ sorted,
    float* __restrict__ node)
{
    __shared__ float smem[32 * 256];   // 32KB: [msg 32x128 | val 32x128], later val2 32x256
    __shared__ float attr_s[32][4];
    __shared__ float wgt_s[32][H_];
    __shared__ int   dst_s[32];
    __shared__ int   eid_s[32];
    float* msg_s = smem;           // [32][128]
    float* val_s = smem + 4096;    // [32][128]
    const int t = threadIdx.x;
    const int b0 = blockIdx.x * 32;

    if (t < 32) {
        const int e = sorted[b0 + t];
        eid_s[t] = e;
        dst_s[t] = edge_dst[e];
        *(float4*)&attr_s[t][0] = *(const float4*)&edge_attr[(long)e * A_];
    }
    __syncthreads();
    #pragma unroll
    for (int i = 0; i < 4; i++) {
        const int idx = t + i * 256;
        const int el = idx >> 5, c4 = (idx & 31) * 4;
        *(float4*)&msg_s[el * C_ + c4] = *(const float4*)&msg[(long)eid_s[el] * C_ + c4];
    }
    {   // softmax weights, one (el,h) per thread
        const int el = t >> 3, h = t & 7;
        const long e = eid_s[el];
        const int n = dst_s[el];
        const float am = dec(amax_u[n * H_ + h]);
        const float d  = denom[n * H_ + h];
        wgt_s[el][h] = __expf(logits[e * H_ + h] - am) / (d + 1e-16f);
    }
    __syncthreads();
    {   // phase 1: gate GEMM, 8 edges x 2 cols per thread
        const int c2 = t & 63;
        const int g  = t >> 6;
        float2 acc[8];
        const float ba = b_lin_act[c2], bb = b_lin_act[c2 + 64];
        #pragma unroll
        for (int i = 0; i < 8; i++) { acc[i].x = ba; acc[i].y = bb; }
        const float* wp = w_lin_act + c2;
        for (int c4 = 0; c4 < 32; c4++) {
            const float wa0 = wp[(c4*4+0)*C_], wb0 = wp[(c4*4+0)*C_ + 64];
            const float wa1 = wp[(c4*4+1)*C_], wb1 = wp[(c4*4+1)*C_ + 64];
            const float wa2 = wp[(c4*4+2)*C_], wb2 = wp[(c4*4+2)*C_ + 64];
            const float wa3 = wp[(c4*4+3)*C_], wb3 = wp[(c4*4+3)*C_ + 64];
            #pragma unroll
            for (int i = 0; i < 8; i++) {
                const float4 mv = *(const float4*)&msg_s[(g * 8 + i) * C_ + c4 * 4];
                acc[i].x += mv.x * wa0 + mv.y * wa1 + mv.z * wa2 + mv.w * wa3;
                acc[i].y += mv.x * wb0 + mv.y * wb1 + mv.z * wb2 + mv.w * wb3;
            }
        }
        const float4 wdva = *(const float4*)&w_dtp_v[c2 * 4];
        const float4 wdvb = *(const float4*)&w_dtp_v[(c2 + 64) * 4];
        #pragma unroll
        for (int i = 0; i < 8; i++) {
            const int el = g * 8 + i;
            const float4 a4 = *(const float4*)&attr_s[el][0];
            const float dva = wdva.x*a4.x + wdva.y*a4.y + wdva.z*a4.z + wdva.w*a4.w;
            const float dvb = wdvb.x*a4.x + wdvb.y*a4.y + wdvb.z*a4.z + wdvb.w*a4.w;
            const float xa = acc[i].x, xb = acc[i].y;
            val_s[el * C_ + c2]      = xa * sigf(xa) * dva;
            val_s[el * C_ + c2 + 64] = xb * sigf(xb) * dvb;
        }
    }
    __syncthreads();
    // phase 2: value GEMM; keep weighted results in registers
    const int j0 = (t & 63) * 4;
    const int g  = t >> 6;
    float4 acc4[8];
    {
        const float4 b = *(const float4*)&b_lin_v[j0];
        #pragma unroll
        for (int i = 0; i < 8; i++) acc4[i] = b;
        const float* wp = w_lin_v + j0;
        for (int c4 = 0; c4 < 32; c4++) {
            const float4 w0 = *(const float4*)&wp[(c4 * 4 + 0) * AH_];
            const float4 w1 = *(const float4*)&wp[(c4 * 4 + 1) * AH_];
            const float4 w2 = *(const float4*)&wp[(c4 * 4 + 2) * AH_];
            const float4 w3 = *(const float4*)&wp[(c4 * 4 + 3) * AH_];
            #pragma unroll
            for (int i = 0; i < 8; i++) {
                const float4 vv = *(const float4*)&val_s[(g * 8 + i) * C_ + c4 * 4];
                acc4[i].x += vv.x * w0.x + vv.y * w1.x + vv.z * w2.x + vv.w * w3.x;
                acc4[i].y += vv.x * w0.y + vv.y * w1.y + vv.z * w2.y + vv.w * w3.y;
                acc4[i].z += vv.x * w0.z + vv.y * w1.z + vv.z * w2.z + vv.w * w3.z;
                acc4[i].w += vv.x * w0.w + vv.y * w1.w + vv.z * w2.w + vv.w * w3.w;
            }
        }
    }
    __syncthreads();   // all reads of val_s done; smem can be overwritten
    {
        const int h = j0 >> 5;
        #pragma unroll
        for (int i = 0; i < 8; i++) {
            const int el = g * 8 + i;
            const float w = wgt_s[el][h];
            float4 v = acc4[i];
            v.x *= w; v.y *= w; v.z *= w; v.w *= w;
            *(float4*)&smem[el * AH_ + j0] = v;   // val2[32][256]
        }
    }
    __syncthreads();
    {   // run-length reduce by dst; thread t owns channel t
        const int c = t;
        float run = 0.f;
        int s = 0;
        #pragma unroll 1
        for (int e = 0; e < 32; e++) {
            run += smem[e * AH_ + c];
            const bool end = (e == 31) || (dst_s[e + 1] != dst_s[e]);
            if (end) {
                float* np = node + (long)dst_s[e] * AH_ + c;
                if (s == 0 || e == 31) atomicAdd(np, run);
                else *np = run;
                run = 0.f; s = e + 1;
            }
        }
    }
}

// K5: out = node @ w_proj + b_proj
__global__ __launch_bounds__(256) void k_proj(
    const float* __restrict__ node, const float* __restrict__ w_proj,
    const float* __restrict__ b_proj, float* __restrict__ out)
{
    __shared__ float node_s[32][AH_];   // 32KB
    const int t = threadIdx.x;
    const long n0 = (long)blockIdx.x * 32;
    #pragma unroll
    for (int i = 0; i < 8; i++) {
        const int idx = t + i * 256;
        const int nl = idx >> 6, c4 = (idx & 63) * 4;
        *(float4*)&node_s[nl][c4] = *(const float4*)&node[(n0 + nl) * AH_ + c4];
    }
    __syncthreads();
    const int j0 = (t & 31) * 4;
    const int g  = t >> 5;     // 8 groups x 4 nodes
    float4 acc4[4];
    const float4 b = *(const float4*)&b_proj[j0];
    #pragma unroll
    for (int i = 0; i < 4; i++) acc4[i] = b;
    const float* wp = w_proj + j0;
    for (int c4 = 0; c4 < 64; c4++) {
        const float4 w0 = *(const float4*)&wp[(c4 * 4 + 0) * OUT_];
        const float4 w1 = *(const float4*)&wp[(c4 * 4 + 1) * OUT_];
        const float4 w2 = *(const float4*)&wp[(c4 * 4 + 2) * OUT_];
        const float4 w3 = *(const float4*)&wp[(c4 * 4 + 3) * OUT_];
        #pragma unroll
        for (int i = 0; i < 4; i++) {
            const float4 nv = *(const float4*)&node_s[g * 4 + i][c4 * 4];
            acc4[i].x += nv.x * w0.x + nv.y * w1.x + nv.z * w2.x + nv.w * w3.x;
            acc4[i].y += nv.x * w0.y + nv.y * w1.y + nv.z * w2.y + nv.w * w3.y;
            acc4[i].z += nv.x * w0.z + nv.y * w1.z + nv.z * w2.z + nv.w * w3.z;
            acc4[i].w += nv.x * w0.w + nv.y * w1.w + nv.z * w2.w + nv.w * w3.w;
        }
    }
    #pragma unroll
    for (int i = 0; i < 4; i++) {
        const long n = n0 + g * 4 + i;
        *(float4*)&out[n * OUT_ + j0] = acc4[i];
    }
}

extern "C" void kernel_launch(void* const* d_in, const int* in_sizes, int n_in,
                              void* d_out, int out_size, void* d_ws, size_t ws_size,
                              hipStream_t stream)
{
    const float* message      = (const float*)d_in[0];
    const float* edge_attr    = (const float*)d_in[1];
    const float* edge_scalars = (const float*)d_in[2];
    const float* w_rad1       = (const float*)d_in[3];
    const float* b_rad1       = (const float*)d_in[4];
    const float* w_rad2       = (const float*)d_in[5];
    const float* b_rad2       = (const float*)d_in[6];
    const float* w_dtp_v      = (const float*)d_in[7];
    const float* w_lin_act    = (const float*)d_in[8];
    const float* b_lin_act    = (const float*)d_in[9];
    const float* w_alpha      = (const float*)d_in[10];
    const float* b_alpha      = (const float*)d_in[11];
    const float* w_lin_v      = (const float*)d_in[12];
    const float* b_lin_v      = (const float*)d_in[13];
    const float* alpha_dot    = (const float*)d_in[14];
    const float* w_proj       = (const float*)d_in[15];
    const float* b_proj       = (const float*)d_in[16];
    const int*   edge_dst     = (const int*)d_in[17];

    const int E = in_sizes[0] / C_;
    const int N = out_size / OUT_;

    // ws layout (all f32/i32, zeroed region first):
    // [node N*256][amax N*8][denom N*8][deg N] | [base N][cursor N][sorted E][msg E*128][logits E*8]
    char* ws = (char*)d_ws;
    float*    node   = (float*)ws;
    unsigned* amax_u = (unsigned*)(node + (size_t)N * AH_);
    float*    denom  = (float*)(amax_u + (size_t)N * H_);
    int*      deg    = (int*)(denom + (size_t)N * H_);
    int*      base   = deg + N;
    int*      cursor = base + N;
    int*      sorted = cursor + N;
    float*    msg    = (float*)(sorted + E);
    float*    logits = msg + (size_t)E * C_;

    // zero node + amax (enc: 0 < any finite) + denom + deg
    hipMemsetAsync(d_ws, 0, (size_t)N * (AH_ + 2 * H_ + 1) * 4, stream);

    const int nbE = E / 32;
    const int nbE256 = (E + 255) / 256;
    k_hist <<<nbE256, 256, 0, stream>>>(edge_dst, deg, E);
    k_scan <<<1, 1024, 0, stream>>>(deg, base, cursor, N);
    k_fill <<<nbE256, 256, 0, stream>>>(edge_dst, cursor, sorted, E);
    k_msg  <<<nbE, 256, 0, stream>>>(message, edge_attr, edge_scalars,
                                     w_rad1, b_rad1, w_rad2, b_rad2, msg);
    k_alpha<<<nbE, 256, 0, stream>>>(msg, w_alpha, b_alpha, alpha_dot, edge_dst,
                                     logits, amax_u);
    k_denom<<<(E * H_ + 255) / 256, 256, 0, stream>>>(logits, edge_dst, amax_u, denom, E * H_);
    k_value<<<nbE, 256, 0, stream>>>(msg, edge_attr, w_lin_act, b_lin_act, w_dtp_v,
                                     w_lin_v, b_lin_v, logits, edge_dst, amax_u, denom,
                                     sorted, node);
    k_proj <<<N / 32, 256, 0, stream>>>(node, w_proj, b_proj, (float*)d_out);
}

// Round 3
// 726.691 us; speedup vs baseline: 2.9729x; 2.1629x over previous
//
#include <hip/hip_runtime.h>

#define C_   128
#define A_   4
#define S_   16
#define RH_  64
#define H_   8
#define AH_  256
#define OUT_ 128

typedef __attribute__((ext_vector_type(8))) short bf16x8;
typedef __attribute__((ext_vector_type(4))) float f32x4;

__device__ __forceinline__ float sigf(float x) { return 1.0f / (1.0f + __expf(-x)); }

__device__ __forceinline__ unsigned short f2bf(float x) {
    unsigned u = __float_as_uint(x);
    unsigned r = (u + 0x7fffu + ((u >> 16) & 1u)) >> 16;   // RNE
    return (unsigned short)r;
}

// monotone float <-> uint mapping for atomicMax-based segment max
__device__ __forceinline__ unsigned enc(float x) {
    unsigned b = __float_as_uint(x);
    return (b & 0x80000000u) ? ~b : (b | 0x80000000u);
}
__device__ __forceinline__ float dec(unsigned u) {
    unsigned b = (u & 0x80000000u) ? (u & 0x7fffffffu) : ~u;
    return __uint_as_float(b);
}

// Pack f32 weight W[K][N] into bf16 fragment-linear layout for mfma_f32_16x16x32_bf16:
// out[((ct*(K/32)+ks)*64 + l)*8 + j] = W[ks*32 + (l>>4)*8 + j][ct*16 + (l&15)]
// grid = (N/16)*(K/32) blocks, 64 threads; blockIdx.x = ct*(K/32)+ks
__global__ void k_pack(const float* __restrict__ W, short* __restrict__ out, int K, int N) {
    const int KS = K / 32;
    const int ct = blockIdx.x / KS, ks = blockIdx.x % KS;
    const int l = threadIdx.x, lr = l & 15, lg = l >> 4;
    bf16x8 v;
    #pragma unroll
    for (int j = 0; j < 8; j++)
        v[j] = (short)f2bf(W[(size_t)(ks * 32 + lg * 8 + j) * N + ct * 16 + lr]);
    *(bf16x8*)&out[((size_t)blockIdx.x * 64 + l) * 8] = v;
}

// CSR build: histogram, scan, fill
__global__ __launch_bounds__(256) void k_hist(
    const int* __restrict__ edge_dst, int* __restrict__ deg, int E)
{
    const int e = blockIdx.x * 256 + threadIdx.x;
    if (e < E) atomicAdd(&deg[edge_dst[e]], 1);
}

__global__ __launch_bounds__(1024) void k_scan(
    const int* __restrict__ deg, int* __restrict__ base, int* __restrict__ cursor, int N)
{
    __shared__ int part[1024];
    const int t = threadIdx.x;
    const int per = (N + 1023) / 1024;
    const int i0 = t * per;
    int s = 0;
    for (int i = 0; i < per; i++) { int idx = i0 + i; if (idx < N) s += deg[idx]; }
    part[t] = s;
    __syncthreads();
    for (int off = 1; off < 1024; off <<= 1) {
        int v = (t >= off) ? part[t - off] : 0;
        __syncthreads();
        part[t] += v;
        __syncthreads();
    }
    int excl = (t == 0) ? 0 : part[t - 1];
    for (int i = 0; i < per; i++) {
        int idx = i0 + i;
        if (idx < N) { base[idx] = excl; cursor[idx] = excl; excl += deg[idx]; }
    }
}

__global__ __launch_bounds__(256) void k_fill(
    const int* __restrict__ edge_dst, int* __restrict__ cursor,
    int* __restrict__ sorted, int E)
{
    const int e = blockIdx.x * 256 + threadIdx.x;
    if (e < E) {
        const int pos = atomicAdd(&cursor[edge_dst[e]], 1);
        sorted[pos] = e;
    }
}

// Fused msg + alpha kernel. 64 edges per block, 256 threads (4 waves).
// Phase A: radial layer-1 (f32 VALU) -> h_s bf16 (swizzled).
// Phase B: MFMA h @ w_rad2_lin -> wfull; tp = sum_a wfull*attr (shfl); msg = message*tp -> msg_s bf16.
// Phase C: msg_s -> global msg_bf (coalesced).
// Phase D: MFMA msg @ w_alpha_lin -> SLR -> dot alpha_dot -> 16-lane reduce -> logits + atomicMax.
__global__ __launch_bounds__(256) void k_msgalpha(
    const float* __restrict__ message, const float* __restrict__ edge_attr,
    const float* __restrict__ edge_scalars,
    const float* __restrict__ w_rad1, const float* __restrict__ b_rad1,
    const short* __restrict__ w_rad2_lin, const float* __restrict__ b_rad2,
    const short* __restrict__ w_alpha_lin, const float* __restrict__ b_alpha,
    const float* __restrict__ alpha_dot, const int* __restrict__ edge_dst,
    short* __restrict__ msg_bf, float* __restrict__ logits, unsigned* __restrict__ amax_u)
{
    __shared__ float w1_s[S_][RH_];                    // 4KB
    __shared__ float es_s[64][17];                     // padded
    __shared__ float attr_s[64][4];
    __shared__ int   dst_s[64];
    __shared__ __align__(16) short h_s[64 * 64];       // 8KB,  row stride 128B, swizzled
    __shared__ __align__(16) short msg_s[64 * 128];    // 16KB, row stride 256B, swizzled
    const int t = threadIdx.x;
    const long e0 = (long)blockIdx.x * 64;

    *(float4*)&((float*)w1_s)[t * 4] = *(const float4*)&w_rad1[t * 4];
    { const int r = t >> 2, s4 = (t & 3) * 4;
      *(float4*)&es_s[r][s4] = *(const float4*)&edge_scalars[(e0 + r) * S_ + s4]; }
    if (t < 64) {
        *(float4*)&attr_s[t][0] = *(const float4*)&edge_attr[(e0 + t) * A_];
        dst_s[t] = edge_dst[e0 + t];
    }
    __syncthreads();

    {   // Phase A: h = silu(es @ w_rad1 + b1), 64 rows x 64 cols; thread: row=t&63, 16 cols
        const int r = t & 63, o0 = (t >> 6) * 16;
        float acc[16];
        #pragma unroll
        for (int i = 0; i < 16; i++) acc[i] = b_rad1[o0 + i];
        #pragma unroll
        for (int s = 0; s < S_; s++) {
            const float ev = es_s[r][s];
            #pragma unroll
            for (int i = 0; i < 16; i++) acc[i] += ev * w1_s[s][o0 + i];
        }
        bf16x8 lo, hi;
        #pragma unroll
        for (int i = 0; i < 8; i++) { float x = acc[i];     lo[i] = (short)f2bf(x * sigf(x)); }
        #pragma unroll
        for (int i = 0; i < 8; i++) { float x = acc[8 + i]; hi[i] = (short)f2bf(x * sigf(x)); }
        char* hp = (char*)h_s + r * 128;
        const int sw = (r & 7) << 4;
        *(bf16x8*)(hp + (((o0 * 2)     ) ^ sw)) = lo;
        *(bf16x8*)(hp + (((o0 * 2) + 16) ^ sw)) = hi;
    }
    __syncthreads();

    const int w = t >> 6, l = t & 63, lr = l & 15, lg = l >> 4;

    {   // Phase B: wfull = h @ w_rad2 + b_rad2 ; tp ; msg
        bf16x8 af[4][2];
        #pragma unroll
        for (int rt = 0; rt < 4; rt++)
            #pragma unroll
            for (int ks = 0; ks < 2; ks++) {
                const int row = rt * 16 + lr;
                af[rt][ks] = *(bf16x8*)((char*)h_s + row * 128 + ((ks * 64 + lg * 16) ^ ((row & 7) << 4)));
            }
        #pragma unroll
        for (int cti = 0; cti < 8; cti++) {
            const int ct = w * 8 + cti;
            const bf16x8 b0 = *(const bf16x8*)&w_rad2_lin[((size_t)(ct * 2 + 0) * 64 + l) * 8];
            const bf16x8 b1 = *(const bf16x8*)&w_rad2_lin[((size_t)(ct * 2 + 1) * 64 + l) * 8];
            const int col = ct * 16 + lr;
            const float b2 = b_rad2[col];
            #pragma unroll
            for (int rt = 0; rt < 4; rt++) {
                f32x4 acc = {0.f, 0.f, 0.f, 0.f};
                acc = __builtin_amdgcn_mfma_f32_16x16x32_bf16(af[rt][0], b0, acc, 0, 0, 0);
                acc = __builtin_amdgcn_mfma_f32_16x16x32_bf16(af[rt][1], b1, acc, 0, 0, 0);
                #pragma unroll
                for (int r = 0; r < 4; r++) {
                    const int row = rt * 16 + lg * 4 + r;
                    float v = (acc[r] + b2) * attr_s[row][l & 3];
                    v += __shfl_xor(v, 1);
                    v += __shfl_xor(v, 2);
                    if ((l & 3) == 0) {
                        const int c = ct * 4 + (lr >> 2);
                        const float m = message[(e0 + row) * C_ + c];
                        *(short*)((char*)msg_s + row * 256 + ((c * 2) ^ ((row & 7) << 4))) =
                            (short)f2bf(m * v);
                    }
                }
            }
        }
    }
    __syncthreads();

    {   // Phase C: msg_s -> global (bf16, coalesced 256B rows)
        #pragma unroll
        for (int i = 0; i < 4; i++) {
            const int row = (t >> 4) + i * 16, ch = t & 15;
            const uint4 v = *(uint4*)((char*)msg_s + row * 256 + ((ch * 16) ^ ((row & 7) << 4)));
            *(uint4*)((char*)msg_bf + ((e0 + row) * 256 + ch * 16)) = v;
        }
    }

    {   // Phase D: alpha GEMM + SLR + head dot
        bf16x8 af[4][4];
        #pragma unroll
        for (int rt = 0; rt < 4; rt++)
            #pragma unroll
            for (int ks = 0; ks < 4; ks++) {
                const int row = rt * 16 + lr;
                af[rt][ks] = *(bf16x8*)((char*)msg_s + row * 256 + ((ks * 64 + lg * 16) ^ ((row & 7) << 4)));
            }
        float part[2][4][4];
        #pragma unroll
        for (int p = 0; p < 2; p++)
            #pragma unroll
            for (int rt = 0; rt < 4; rt++)
                #pragma unroll
                for (int r = 0; r < 4; r++) part[p][rt][r] = 0.f;
        #pragma unroll
        for (int q = 0; q < 4; q++) {
            const int ct = w * 4 + q;
            bf16x8 bf[4];
            #pragma unroll
            for (int ks = 0; ks < 4; ks++)
                bf[ks] = *(const bf16x8*)&w_alpha_lin[((size_t)(ct * 4 + ks) * 64 + l) * 8];
            const int col = ct * 16 + lr;
            const float ba = b_alpha[col], ad = alpha_dot[col];
            #pragma unroll
            for (int rt = 0; rt < 4; rt++) {
                f32x4 acc = {0.f, 0.f, 0.f, 0.f};
                #pragma unroll
                for (int ks = 0; ks < 4; ks++)
                    acc = __builtin_amdgcn_mfma_f32_16x16x32_bf16(af[rt][ks], bf[ks], acc, 0, 0, 0);
                #pragma unroll
                for (int r = 0; r < 4; r++) {
                    const float x = acc[r] + ba;
                    const float y = 0.5f * (1.2f * x + 0.8f * x * (2.0f * sigf(x) - 1.0f));
                    part[q >> 1][rt][r] += y * ad;
                }
            }
        }
        #pragma unroll
        for (int p = 0; p < 2; p++)
            #pragma unroll
            for (int rt = 0; rt < 4; rt++)
                #pragma unroll
                for (int r = 0; r < 4; r++) {
                    float v = part[p][rt][r];
                    v += __shfl_xor(v, 1);
                    v += __shfl_xor(v, 2);
                    v += __shfl_xor(v, 4);
                    v += __shfl_xor(v, 8);
                    if (lr == 0) {
                        const int row = rt * 16 + lg * 4 + r;
                        const int h = w * 2 + p;
                        const long e = e0 + row;
                        logits[e * H_ + h] = v;
                        atomicMax(&amax_u[dst_s[row] * H_ + h], enc(v));
                    }
                }
    }
}

// K3: denom[n,h] += exp(logit - amax)
__global__ __launch_bounds__(256) void k_denom(
    const float* __restrict__ logits, const int* __restrict__ edge_dst,
    const unsigned* __restrict__ amax_u, float* __restrict__ denom, int EH)
{
    const int t = blockIdx.x * 256 + threadIdx.x;
    if (t >= EH) return;
    const int e = t >> 3, h = t & 7;
    const int n = edge_dst[e];
    const float am = dec(amax_u[n * H_ + h]);
    atomicAdd(&denom[n * H_ + h], __expf(logits[t] - am));
}

// K4: dst-sorted edges, 32 per block. MFMA gate + value GEMMs, weighted
// run-length reduce by dst (interior: plain store, boundary: atomicAdd).
__global__ __launch_bounds__(256) void k_value(
    const short* __restrict__ msg_bf, const float* __restrict__ edge_attr,
    const short* __restrict__ w_lin_act_lin, const float* __restrict__ b_lin_act,
    const float* __restrict__ w_dtp_v,
    const short* __restrict__ w_lin_v_lin, const float* __restrict__ b_lin_v,
    const float* __restrict__ logits, const int* __restrict__ edge_dst,
    const unsigned* __restrict__ amax_u, const float* __restrict__ denom,
    const int* __restrict__ sorted, float* __restrict__ node)
{
    __shared__ __align__(16) short a_s[32 * 128];   // 8KB swizzled
    __shared__ __align__(16) short v_s[32 * 128];   // 8KB swizzled
    __shared__ float val2[32 * 260];                // 33.3KB padded stride
    __shared__ float attr_s[32][4];
    __shared__ float wgt_s[32][H_];
    __shared__ int   dst_s[32];
    __shared__ int   eid_s[32];
    const int t = threadIdx.x;
    const int b0 = blockIdx.x * 32;

    if (t < 32) {
        const int e = sorted[b0 + t];
        eid_s[t] = e;
        dst_s[t] = edge_dst[e];
        *(float4*)&attr_s[t][0] = *(const float4*)&edge_attr[(long)e * A_];
    }
    __syncthreads();
    #pragma unroll
    for (int i = 0; i < 2; i++) {   // gather msg rows -> swizzled LDS
        const int row = (t >> 4) + i * 16, ch = t & 15;
        const uint4 v = *(const uint4*)((const char*)msg_bf + ((long)eid_s[row] * 256 + ch * 16));
        *(uint4*)((char*)a_s + row * 256 + ((ch * 16) ^ ((row & 7) << 4))) = v;
    }
    {   // softmax weights
        const int el = t >> 3, h = t & 7;
        const long e = eid_s[el];
        const int n = dst_s[el];
        const float am = dec(amax_u[n * H_ + h]);
        const float d  = denom[n * H_ + h];
        wgt_s[el][h] = __expf(logits[e * H_ + h] - am) / (d + 1e-16f);
    }
    __syncthreads();

    const int w = t >> 6, l = t & 63, lr = l & 15, lg = l >> 4;
    bf16x8 af[2][4];
    #pragma unroll
    for (int rt = 0; rt < 2; rt++)
        #pragma unroll
        for (int ks = 0; ks < 4; ks++) {
            const int row = rt * 16 + lr;
            af[rt][ks] = *(bf16x8*)((char*)a_s + row * 256 + ((ks * 64 + lg * 16) ^ ((row & 7) << 4)));
        }
    #pragma unroll
    for (int q = 0; q < 2; q++) {   // gate GEMM: N=128
        const int ct = w * 2 + q;
        bf16x8 bf[4];
        #pragma unroll
        for (int ks = 0; ks < 4; ks++)
            bf[ks] = *(const bf16x8*)&w_lin_act_lin[((size_t)(ct * 4 + ks) * 64 + l) * 8];
        const int col = ct * 16 + lr;
        const float bb = b_lin_act[col];
        const float4 wv = *(const float4*)&w_dtp_v[col * 4];
        #pragma unroll
        for (int rt = 0; rt < 2; rt++) {
            f32x4 acc = {0.f, 0.f, 0.f, 0.f};
            #pragma unroll
            for (int ks = 0; ks < 4; ks++)
                acc = __builtin_amdgcn_mfma_f32_16x16x32_bf16(af[rt][ks], bf[ks], acc, 0, 0, 0);
            #pragma unroll
            for (int r = 0; r < 4; r++) {
                const int row = rt * 16 + lg * 4 + r;
                float x = acc[r] + bb;
                x = x * sigf(x);
                const float4 a4 = *(const float4*)&attr_s[row][0];
                const float dv = wv.x * a4.x + wv.y * a4.y + wv.z * a4.z + wv.w * a4.w;
                *(short*)((char*)v_s + row * 256 + ((col * 2) ^ ((row & 7) << 4))) =
                    (short)f2bf(x * dv);
            }
        }
    }
    __syncthreads();

    bf16x8 vf[2][4];
    #pragma unroll
    for (int rt = 0; rt < 2; rt++)
        #pragma unroll
        for (int ks = 0; ks < 4; ks++) {
            const int row = rt * 16 + lr;
            vf[rt][ks] = *(bf16x8*)((char*)v_s + row * 256 + ((ks * 64 + lg * 16) ^ ((row & 7) << 4)));
        }
    #pragma unroll
    for (int q = 0; q < 4; q++) {   // value GEMM: N=256
        const int ct = w * 4 + q;
        bf16x8 bf[4];
        #pragma unroll
        for (int ks = 0; ks < 4; ks++)
            bf[ks] = *(const bf16x8*)&w_lin_v_lin[((size_t)(ct * 4 + ks) * 64 + l) * 8];
        const int col = ct * 16 + lr;
        const float bb = b_lin_v[col];
        #pragma unroll
        for (int rt = 0; rt < 2; rt++) {
            f32x4 acc = {0.f, 0.f, 0.f, 0.f};
            #pragma unroll
            for (int ks = 0; ks < 4; ks++)
                acc = __builtin_amdgcn_mfma_f32_16x16x32_bf16(vf[rt][ks], bf[ks], acc, 0, 0, 0);
            #pragma unroll
            for (int r = 0; r < 4; r++) {
                const int row = rt * 16 + lg * 4 + r;
                val2[row * 260 + col] = (acc[r] + bb) * wgt_s[row][col >> 5];
            }
        }
    }
    __syncthreads();
    {   // run-length reduce by dst; thread t owns channel t
        const int c = t;
        float run = 0.f;
        int s = 0;
        #pragma unroll 1
        for (int e = 0; e < 32; e++) {
            run += val2[e * 260 + c];
            const bool end = (e == 31) || (dst_s[e + 1] != dst_s[e]);
            if (end) {
                float* np = node + (long)dst_s[e] * AH_ + c;
                if (s == 0 || e == 31) atomicAdd(np, run);
                else *np = run;
                run = 0.f; s = e + 1;
            }
        }
    }
}

// K5: out = node @ w_proj + b_proj
__global__ __launch_bounds__(256) void k_proj(
    const float* __restrict__ node, const float* __restrict__ w_proj,
    const float* __restrict__ b_proj, float* __restrict__ out)
{
    __shared__ float node_s[32][AH_];   // 32KB
    const int t = threadIdx.x;
    const long n0 = (long)blockIdx.x * 32;
    #pragma unroll
    for (int i = 0; i < 8; i++) {
        const int idx = t + i * 256;
        const int nl = idx >> 6, c4 = (idx & 63) * 4;
        *(float4*)&node_s[nl][c4] = *(const float4*)&node[(n0 + nl) * AH_ + c4];
    }
    __syncthreads();
    const int j0 = (t & 31) * 4;
    const int g  = t >> 5;
    float4 acc4[4];
    const float4 b = *(const float4*)&b_proj[j0];
    #pragma unroll
    for (int i = 0; i < 4; i++) acc4[i] = b;
    const float* wp = w_proj + j0;
    for (int c4 = 0; c4 < 64; c4++) {
        const float4 w0 = *(const float4*)&wp[(c4 * 4 + 0) * OUT_];
        const float4 w1 = *(const float4*)&wp[(c4 * 4 + 1) * OUT_];
        const float4 w2 = *(const float4*)&wp[(c4 * 4 + 2) * OUT_];
        const float4 w3 = *(const float4*)&wp[(c4 * 4 + 3) * OUT_];
        #pragma unroll
        for (int i = 0; i < 4; i++) {
            const float4 nv = *(const float4*)&node_s[g * 4 + i][c4 * 4];
            acc4[i].x += nv.x * w0.x + nv.y * w1.x + nv.z * w2.x + nv.w * w3.x;
            acc4[i].y += nv.x * w0.y + nv.y * w1.y + nv.z * w2.y + nv.w * w3.y;
            acc4[i].z += nv.x * w0.z + nv.y * w1.z + nv.z * w2.z + nv.w * w3.z;
            acc4[i].w += nv.x * w0.w + nv.y * w1.w + nv.z * w2.w + nv.w * w3.w;
        }
    }
    #pragma unroll
    for (int i = 0; i < 4; i++) {
        const long n = n0 + g * 4 + i;
        *(float4*)&out[n * OUT_ + j0] = acc4[i];
    }
}

extern "C" void kernel_launch(void* const* d_in, const int* in_sizes, int n_in,
                              void* d_out, int out_size, void* d_ws, size_t ws_size,
                              hipStream_t stream)
{
    const float* message      = (const float*)d_in[0];
    const float* edge_attr    = (const float*)d_in[1];
    const float* edge_scalars = (const float*)d_in[2];
    const float* w_rad1       = (const float*)d_in[3];
    const float* b_rad1       = (const float*)d_in[4];
    const float* w_rad2       = (const float*)d_in[5];
    const float* b_rad2       = (const float*)d_in[6];
    const float* w_dtp_v      = (const float*)d_in[7];
    const float* w_lin_act    = (const float*)d_in[8];
    const float* b_lin_act    = (const float*)d_in[9];
    const float* w_alpha      = (const float*)d_in[10];
    const float* b_alpha      = (const float*)d_in[11];
    const float* w_lin_v      = (const float*)d_in[12];
    const float* b_lin_v      = (const float*)d_in[13];
    const float* alpha_dot    = (const float*)d_in[14];
    const float* w_proj       = (const float*)d_in[15];
    const float* b_proj       = (const float*)d_in[16];
    const int*   edge_dst     = (const int*)d_in[17];

    const int E = in_sizes[0] / C_;
    const int N = out_size / OUT_;

    // ws layout (zeroed region first):
    // [node N*256 f32][amax N*8 u32][denom N*8 f32][deg N i32] |
    // [base N][cursor N][sorted E][w_rad2_lin 32768s][w_alpha_lin 32768s]
    // [w_lin_act_lin 16384s][w_lin_v_lin 32768s][msg_bf E*128 s][logits E*8 f32]
    char* ws = (char*)d_ws;
    float*    node     = (float*)ws;
    unsigned* amax_u   = (unsigned*)(node + (size_t)N * AH_);
    float*    denom    = (float*)(amax_u + (size_t)N * H_);
    int*      deg      = (int*)(denom + (size_t)N * H_);
    int*      base     = deg + N;
    int*      cursor   = base + N;
    int*      sorted   = cursor + N;
    short*    w_rad2_l = (short*)(sorted + E);
    short*    w_alph_l = w_rad2_l + 64 * 512;
    short*    w_lact_l = w_alph_l + 128 * 256;
    short*    w_linv_l = w_lact_l + 128 * 128;
    short*    msg_bf   = w_linv_l + 128 * 256;
    float*    logits   = (float*)(msg_bf + (size_t)E * C_);

    hipMemsetAsync(d_ws, 0, (size_t)N * (AH_ + 2 * H_ + 1) * 4, stream);

    const int nbE256 = (E + 255) / 256;
    k_pack<<<(512/16)*(64/32),  64, 0, stream>>>(w_rad2,    w_rad2_l, 64,  512);
    k_pack<<<(256/16)*(128/32), 64, 0, stream>>>(w_alpha,   w_alph_l, 128, 256);
    k_pack<<<(128/16)*(128/32), 64, 0, stream>>>(w_lin_act, w_lact_l, 128, 128);
    k_pack<<<(256/16)*(128/32), 64, 0, stream>>>(w_lin_v,   w_linv_l, 128, 256);
    k_hist<<<nbE256, 256, 0, stream>>>(edge_dst, deg, E);
    k_scan<<<1, 1024, 0, stream>>>(deg, base, cursor, N);
    k_fill<<<nbE256, 256, 0, stream>>>(edge_dst, cursor, sorted, E);
    k_msgalpha<<<E / 64, 256, 0, stream>>>(message, edge_attr, edge_scalars,
                                           w_rad1, b_rad1, w_rad2_l, b_rad2,
                                           w_alph_l, b_alpha, alpha_dot, edge_dst,
                                           msg_bf, logits, amax_u);
    k_denom<<<(E * H_ + 255) / 256, 256, 0, stream>>>(logits, edge_dst, amax_u, denom, E * H_);
    k_value<<<E / 32, 256, 0, stream>>>(msg_bf, edge_attr, w_lact_l, b_lin_act, w_dtp_v,
                                        w_linv_l, b_lin_v, logits, edge_dst, amax_u, denom,
                                        sorted, node);
    k_proj<<<N / 32, 256, 0, stream>>>(node, w_proj, b_proj, (float*)d_out);
}

// Round 4
// 423.891 us; speedup vs baseline: 5.0965x; 1.7143x over previous
//
#include <hip/hip_runtime.h>

#define C_   128
#define A_   4
#define S_   16
#define RH_  64
#define H_   8
#define AH_  256
#define OUT_ 128

typedef __attribute__((ext_vector_type(8))) short bf16x8;
typedef __attribute__((ext_vector_type(4))) float f32x4;

__device__ __forceinline__ float sigf(float x) { return 1.0f / (1.0f + __expf(-x)); }

__device__ __forceinline__ unsigned short f2bf(float x) {
    unsigned u = __float_as_uint(x);
    unsigned r = (u + 0x7fffu + ((u >> 16) & 1u)) >> 16;   // RNE
    return (unsigned short)r;
}

// monotone float <-> uint mapping for atomicMax-based segment max
__device__ __forceinline__ unsigned enc(float x) {
    unsigned b = __float_as_uint(x);
    return (b & 0x80000000u) ? ~b : (b | 0x80000000u);
}
__device__ __forceinline__ float dec(unsigned u) {
    unsigned b = (u & 0x80000000u) ? (u & 0x7fffffffu) : ~u;
    return __uint_as_float(b);
}

// Pack f32 weight W[K][N] into bf16 fragment-linear layout for mfma_f32_16x16x32_bf16:
// out[((ct*(K/32)+ks)*64 + l)*8 + j] = W[ks*32 + (l>>4)*8 + j][ct*16 + (l&15)]
// Serves as B-fragment of W, or equivalently A-fragment of W^T.
__global__ void k_pack(const float* __restrict__ W, short* __restrict__ out, int K, int N) {
    const int KS = K / 32;
    const int ct = blockIdx.x / KS, ks = blockIdx.x % KS;
    const int l = threadIdx.x, lr = l & 15, lg = l >> 4;
    bf16x8 v;
    #pragma unroll
    for (int j = 0; j < 8; j++)
        v[j] = (short)f2bf(W[(size_t)(ks * 32 + lg * 8 + j) * N + ct * 16 + lr]);
    *(bf16x8*)&out[((size_t)blockIdx.x * 64 + l) * 8] = v;
}

// Pack w_rad2 [64][512] as B'[k][c] with k = r*4+a (K=256), c in [0,128):
// B'[k][c] = w_rad2[k>>2][c*4 + (k&3)]
__global__ void k_pack_dtp(const float* __restrict__ W, short* __restrict__ out) {
    const int ct = blockIdx.x >> 3, ks = blockIdx.x & 7;   // ct 0..7, ks 0..7
    const int l = threadIdx.x, lr = l & 15, lg = l >> 4;
    bf16x8 v;
    #pragma unroll
    for (int j = 0; j < 8; j++)
        v[j] = (short)f2bf(W[(size_t)(ks * 8 + lg * 2 + (j >> 2)) * 512 + (ct * 16 + lr) * 4 + (j & 3)]);
    *(bf16x8*)&out[((size_t)blockIdx.x * 64 + l) * 8] = v;
}

// CSR build: histogram, scan, fill
__global__ __launch_bounds__(256) void k_hist(
    const int* __restrict__ edge_dst, int* __restrict__ deg, int E)
{
    const int e = blockIdx.x * 256 + threadIdx.x;
    if (e < E) atomicAdd(&deg[edge_dst[e]], 1);
}

__global__ __launch_bounds__(1024) void k_scan(
    const int* __restrict__ deg, int* __restrict__ base, int* __restrict__ cursor, int N)
{
    __shared__ int part[1024];
    const int t = threadIdx.x;
    const int per = (N + 1023) / 1024;
    const int i0 = t * per;
    int s = 0;
    for (int i = 0; i < per; i++) { int idx = i0 + i; if (idx < N) s += deg[idx]; }
    part[t] = s;
    __syncthreads();
    for (int off = 1; off < 1024; off <<= 1) {
        int v = (t >= off) ? part[t - off] : 0;
        __syncthreads();
        part[t] += v;
        __syncthreads();
    }
    int excl = (t == 0) ? 0 : part[t - 1];
    for (int i = 0; i < per; i++) {
        int idx = i0 + i;
        if (idx < N) { base[idx] = excl; cursor[idx] = excl; excl += deg[idx]; }
    }
}

__global__ __launch_bounds__(256) void k_fill(
    const int* __restrict__ edge_dst, int* __restrict__ cursor,
    int* __restrict__ sorted, int E)
{
    const int e = blockIdx.x * 256 + threadIdx.x;
    if (e < E) {
        const int pos = atomicAdd(&cursor[edge_dst[e]], 1);
        sorted[pos] = e;
    }
}

// Fused msg + alpha. 64 edges/block, 512 threads (8 waves).
// A: radial layer-1 (f32) -> A' = h (x) attr expansion, bf16 swizzled LDS.
// B: msg-mult = A'(64x256) @ B'(256x128) MFMA (wave w owns col-tile w);
//    epilogue: + attr.b_rad2, * message -> msg_s bf16 (swizzled).
// C: msg_s -> global msg_bf.
// D: transposed alpha GEMM D[ch,e] = w_alpha^T @ msg^T; wave w owns head w;
//    SLR + dot(alpha_dot) in-lane, 2 shfls -> logits + atomicMax.
__global__ __launch_bounds__(512, 4) void k_msgalpha(
    const float* __restrict__ message, const float* __restrict__ edge_attr,
    const float* __restrict__ edge_scalars,
    const float* __restrict__ w_rad1, const float* __restrict__ b_rad1,
    const short* __restrict__ w_rad2_lin, const float* __restrict__ b_rad2,
    const short* __restrict__ w_alpha_lin, const float* __restrict__ b_alpha,
    const float* __restrict__ alpha_dot, const int* __restrict__ edge_dst,
    short* __restrict__ msg_bf, float* __restrict__ logits, unsigned* __restrict__ amax_u)
{
    // LDS: [A' 64x512B = 32768][msg_s 64x256B = 16384 (overlays w1_s 4096 + es_s 4352)]
    //      [attr_s 1024][dst_s 256]  total 50432
    __shared__ __align__(16) char smem[50432];
    short* Ap     = (short*)smem;                       // A' row stride 512B
    short* msg_s  = (short*)(smem + 32768);             // row stride 256B
    float* w1_s   = (float*)(smem + 32768);             // [16][64] overlay
    float* es_s   = (float*)(smem + 32768 + 4096);      // [64][17] overlay
    float* attr_s = (float*)(smem + 49152);             // [64][4]
    int*   dst_s  = (int*)(smem + 50176);               // [64]

    const int t = threadIdx.x;
    const long e0 = (long)blockIdx.x * 64;

    if (t < 256) {
        *(float4*)&w1_s[t * 4] = *(const float4*)&w_rad1[t * 4];
    } else {
        const int i = t - 256, r = i >> 2, s4 = (i & 3) * 4;
        *(float4*)&es_s[r * 17 + s4] = *(const float4*)&edge_scalars[(e0 + r) * S_ + s4];
    }
    if (t < 64) {
        *(float4*)&attr_s[t * 4] = *(const float4*)&edge_attr[(e0 + t) * A_];
        dst_s[t] = edge_dst[e0 + t];
    }
    __syncthreads();

    {   // Phase A: h = silu(es @ w_rad1 + b1); A'[r, 4c+a] = h[r,c]*attr[r,a]
        const int r = t & 63, o0 = (t >> 6) * 8;
        float acc[8];
        #pragma unroll
        for (int i = 0; i < 8; i++) acc[i] = b_rad1[o0 + i];
        #pragma unroll
        for (int s = 0; s < S_; s++) {
            const float ev = es_s[r * 17 + s];
            #pragma unroll
            for (int i = 0; i < 8; i++) acc[i] += ev * w1_s[s * 64 + o0 + i];
        }
        float h[8];
        #pragma unroll
        for (int i = 0; i < 8; i++) { const float x = acc[i]; h[i] = x * sigf(x); }
        const float4 a4 = *(const float4*)&attr_s[r * 4];
        char* base = (char*)Ap + r * 512;
        const int sw = (r & 31) << 4;
        #pragma unroll
        for (int c = 0; c < 4; c++) {
            const float h0 = h[2 * c], h1 = h[2 * c + 1];
            bf16x8 v;
            v[0] = (short)f2bf(h0 * a4.x); v[1] = (short)f2bf(h0 * a4.y);
            v[2] = (short)f2bf(h0 * a4.z); v[3] = (short)f2bf(h0 * a4.w);
            v[4] = (short)f2bf(h1 * a4.x); v[5] = (short)f2bf(h1 * a4.y);
            v[6] = (short)f2bf(h1 * a4.z); v[7] = (short)f2bf(h1 * a4.w);
            *(bf16x8*)(base + ((o0 * 8 + c * 16) ^ sw)) = v;
        }
    }
    __syncthreads();

    const int w = t >> 6, l = t & 63, lr = l & 15, lg = l >> 4;

    {   // Phase B: tp = A' @ B' + attr.b_rad2; msg = message * tp
        bf16x8 bf[8];
        #pragma unroll
        for (int ks = 0; ks < 8; ks++)
            bf[ks] = *(const bf16x8*)&w_rad2_lin[((size_t)(w * 8 + ks) * 64 + l) * 8];
        const int col = w * 16 + lr;
        const float4 b2 = *(const float4*)&b_rad2[col * 4];
        #pragma unroll 1
        for (int rt = 0; rt < 4; rt++) {
            const int arow = rt * 16 + lr;
            const char* abase = (char*)Ap + arow * 512;
            const int asw = (arow & 31) << 4;
            bf16x8 af[8];
            #pragma unroll
            for (int ks = 0; ks < 8; ks++)
                af[ks] = *(const bf16x8*)(abase + ((ks * 64 + lg * 16) ^ asw));
            f32x4 acc = {0.f, 0.f, 0.f, 0.f};
            #pragma unroll
            for (int ks = 0; ks < 8; ks++)
                acc = __builtin_amdgcn_mfma_f32_16x16x32_bf16(af[ks], bf[ks], acc, 0, 0, 0);
            #pragma unroll
            for (int r = 0; r < 4; r++) {
                const int row = rt * 16 + lg * 4 + r;
                const float4 a4 = *(const float4*)&attr_s[row * 4];
                const float badj = a4.x * b2.x + a4.y * b2.y + a4.z * b2.z + a4.w * b2.w;
                const float m = message[(e0 + row) * C_ + col];
                *(short*)((char*)msg_s + row * 256 + ((col * 2) ^ ((row & 15) << 4))) =
                    (short)f2bf(m * (acc[r] + badj));
            }
        }
    }
    __syncthreads();

    {   // Phase C: msg_s -> global (linear bf16 rows)
        #pragma unroll
        for (int i = 0; i < 2; i++) {
            const int q = t + i * 512;
            const int row = q >> 4, ch = q & 15;
            const uint4 v = *(const uint4*)((char*)msg_s + row * 256 + ((ch * 16) ^ ((row & 15) << 4)));
            *(uint4*)((char*)msg_bf + ((e0 + row) * 256 + ch * 16)) = v;
        }
    }

    {   // Phase D: wave w computes head w for all 64 edges
        bf16x8 waf[2][4];
        float4 ba4[2], ad4[2];
        #pragma unroll
        for (int q = 0; q < 2; q++) {
            const int rt = w * 2 + q;
            #pragma unroll
            for (int ks = 0; ks < 4; ks++)
                waf[q][ks] = *(const bf16x8*)&w_alpha_lin[((size_t)(rt * 4 + ks) * 64 + l) * 8];
            ba4[q] = *(const float4*)&b_alpha[rt * 16 + lg * 4];
            ad4[q] = *(const float4*)&alpha_dot[rt * 16 + lg * 4];
        }
        #pragma unroll 1
        for (int ct = 0; ct < 4; ct++) {
            const int erow = ct * 16 + lr;
            const char* mbase = (char*)msg_s + erow * 256;
            const int msw = (erow & 15) << 4;
            bf16x8 mb[4];
            #pragma unroll
            for (int ks = 0; ks < 4; ks++)
                mb[ks] = *(const bf16x8*)(mbase + ((ks * 64 + lg * 16) ^ msw));
            float s = 0.f;
            #pragma unroll
            for (int q = 0; q < 2; q++) {
                f32x4 acc = {0.f, 0.f, 0.f, 0.f};
                #pragma unroll
                for (int ks = 0; ks < 4; ks++)
                    acc = __builtin_amdgcn_mfma_f32_16x16x32_bf16(waf[q][ks], mb[ks], acc, 0, 0, 0);
                #pragma unroll
                for (int r = 0; r < 4; r++) {
                    const float x = acc[r] + ((const float*)&ba4[q])[r];
                    const float y = x * (0.2f + 0.8f * sigf(x));   // SmoothLeakyReLU, a=0.2
                    s += y * ((const float*)&ad4[q])[r];
                }
            }
            s += __shfl_xor(s, 16);
            s += __shfl_xor(s, 32);
            if (lg == 0) {
                const long e = e0 + ct * 16 + lr;
                logits[e * H_ + w] = s;
                atomicMax(&amax_u[dst_s[ct * 16 + lr] * H_ + w], enc(s));
            }
        }
    }
}

// K3: denom[n,h] += exp(logit - amax)
__global__ __launch_bounds__(256) void k_denom(
    const float* __restrict__ logits, const int* __restrict__ edge_dst,
    const unsigned* __restrict__ amax_u, float* __restrict__ denom, int EH)
{
    const int t = blockIdx.x * 256 + threadIdx.x;
    if (t >= EH) return;
    const int e = t >> 3, h = t & 7;
    const int n = edge_dst[e];
    const float am = dec(amax_u[n * H_ + h]);
    atomicAdd(&denom[n * H_ + h], __expf(logits[t] - am));
}

// K4: dst-sorted edges, 32 per block. MFMA gate + value GEMMs, weighted
// run-length reduce by dst (interior: plain store, boundary: atomicAdd).
__global__ __launch_bounds__(256) void k_value(
    const short* __restrict__ msg_bf, const float* __restrict__ edge_attr,
    const short* __restrict__ w_lin_act_lin, const float* __restrict__ b_lin_act,
    const float* __restrict__ w_dtp_v,
    const short* __restrict__ w_lin_v_lin, const float* __restrict__ b_lin_v,
    const float* __restrict__ logits, const int* __restrict__ edge_dst,
    const unsigned* __restrict__ amax_u, const float* __restrict__ denom,
    const int* __restrict__ sorted, float* __restrict__ node)
{
    __shared__ __align__(16) short a_s[32 * 128];   // 8KB swizzled
    __shared__ __align__(16) short v_s[32 * 128];   // 8KB swizzled
    __shared__ float val2[32 * 260];                // 33.3KB padded stride
    __shared__ float attr_s[32][4];
    __shared__ float wgt_s[32][H_];
    __shared__ int   dst_s[32];
    __shared__ int   eid_s[32];
    const int t = threadIdx.x;
    const int b0 = blockIdx.x * 32;

    if (t < 32) {
        const int e = sorted[b0 + t];
        eid_s[t] = e;
        dst_s[t] = edge_dst[e];
        *(float4*)&attr_s[t][0] = *(const float4*)&edge_attr[(long)e * A_];
    }
    __syncthreads();
    #pragma unroll
    for (int i = 0; i < 2; i++) {   // gather msg rows -> swizzled LDS
        const int row = (t >> 4) + i * 16, ch = t & 15;
        const uint4 v = *(const uint4*)((const char*)msg_bf + ((long)eid_s[row] * 256 + ch * 16));
        *(uint4*)((char*)a_s + row * 256 + ((ch * 16) ^ ((row & 7) << 4))) = v;
    }
    {   // softmax weights
        const int el = t >> 3, h = t & 7;
        const long e = eid_s[el];
        const int n = dst_s[el];
        const float am = dec(amax_u[n * H_ + h]);
        const float d  = denom[n * H_ + h];
        wgt_s[el][h] = __expf(logits[e * H_ + h] - am) / (d + 1e-16f);
    }
    __syncthreads();

    const int w = t >> 6, l = t & 63, lr = l & 15, lg = l >> 4;
    bf16x8 af[2][4];
    #pragma unroll
    for (int rt = 0; rt < 2; rt++)
        #pragma unroll
        for (int ks = 0; ks < 4; ks++) {
            const int row = rt * 16 + lr;
            af[rt][ks] = *(bf16x8*)((char*)a_s + row * 256 + ((ks * 64 + lg * 16) ^ ((row & 7) << 4)));
        }
    #pragma unroll
    for (int q = 0; q < 2; q++) {   // gate GEMM: N=128
        const int ct = w * 2 + q;
        bf16x8 bf[4];
        #pragma unroll
        for (int ks = 0; ks < 4; ks++)
            bf[ks] = *(const bf16x8*)&w_lin_act_lin[((size_t)(ct * 4 + ks) * 64 + l) * 8];
        const int col = ct * 16 + lr;
        const float bb = b_lin_act[col];
        const float4 wv = *(const float4*)&w_dtp_v[col * 4];
        #pragma unroll
        for (int rt = 0; rt < 2; rt++) {
            f32x4 acc = {0.f, 0.f, 0.f, 0.f};
            #pragma unroll
            for (int ks = 0; ks < 4; ks++)
                acc = __builtin_amdgcn_mfma_f32_16x16x32_bf16(af[rt][ks], bf[ks], acc, 0, 0, 0);
            #pragma unroll
            for (int r = 0; r < 4; r++) {
                const int row = rt * 16 + lg * 4 + r;
                float x = acc[r] + bb;
                x = x * sigf(x);
                const float4 a4 = *(const float4*)&attr_s[row][0];
                const float dv = wv.x * a4.x + wv.y * a4.y + wv.z * a4.z + wv.w * a4.w;
                *(short*)((char*)v_s + row * 256 + ((col * 2) ^ ((row & 7) << 4))) =
                    (short)f2bf(x * dv);
            }
        }
    }
    __syncthreads();

    bf16x8 vf[2][4];
    #pragma unroll
    for (int rt = 0; rt < 2; rt++)
        #pragma unroll
        for (int ks = 0; ks < 4; ks++) {
            const int row = rt * 16 + lr;
            vf[rt][ks] = *(bf16x8*)((char*)v_s + row * 256 + ((ks * 64 + lg * 16) ^ ((row & 7) << 4)));
        }
    #pragma unroll
    for (int q = 0; q < 4; q++) {   // value GEMM: N=256
        const int ct = w * 4 + q;
        bf16x8 bf[4];
        #pragma unroll
        for (int ks = 0; ks < 4; ks++)
            bf[ks] = *(const bf16x8*)&w_lin_v_lin[((size_t)(ct * 4 + ks) * 64 + l) * 8];
        const int col = ct * 16 + lr;
        const float bb = b_lin_v[col];
        #pragma unroll
        for (int rt = 0; rt < 2; rt++) {
            f32x4 acc = {0.f, 0.f, 0.f, 0.f};
            #pragma unroll
            for (int ks = 0; ks < 4; ks++)
                acc = __builtin_amdgcn_mfma_f32_16x16x32_bf16(vf[rt][ks], bf[ks], acc, 0, 0, 0);
            #pragma unroll
            for (int r = 0; r < 4; r++) {
                const int row = rt * 16 + lg * 4 + r;
                val2[row * 260 + col] = (acc[r] + bb) * wgt_s[row][col >> 5];
            }
        }
    }
    __syncthreads();
    {   // run-length reduce by dst; thread t owns channel t
        const int c = t;
        float run = 0.f;
        int s = 0;
        #pragma unroll 1
        for (int e = 0; e < 32; e++) {
            run += val2[e * 260 + c];
            const bool end = (e == 31) || (dst_s[e + 1] != dst_s[e]);
            if (end) {
                float* np = node + (long)dst_s[e] * AH_ + c;
                if (s == 0 || e == 31) atomicAdd(np, run);
                else *np = run;
                run = 0.f; s = e + 1;
            }
        }
    }
}

// K5: out = node @ w_proj + b_proj
__global__ __launch_bounds__(256) void k_proj(
    const float* __restrict__ node, const float* __restrict__ w_proj,
    const float* __restrict__ b_proj, float* __restrict__ out)
{
    __shared__ float node_s[32][AH_];   // 32KB
    const int t = threadIdx.x;
    const long n0 = (long)blockIdx.x * 32;
    #pragma unroll
    for (int i = 0; i < 8; i++) {
        const int idx = t + i * 256;
        const int nl = idx >> 6, c4 = (idx & 63) * 4;
        *(float4*)&node_s[nl][c4] = *(const float4*)&node[(n0 + nl) * AH_ + c4];
    }
    __syncthreads();
    const int j0 = (t & 31) * 4;
    const int g  = t >> 5;
    float4 acc4[4];
    const float4 b = *(const float4*)&b_proj[j0];
    #pragma unroll
    for (int i = 0; i < 4; i++) acc4[i] = b;
    const float* wp = w_proj + j0;
    for (int c4 = 0; c4 < 64; c4++) {
        const float4 w0 = *(const float4*)&wp[(c4 * 4 + 0) * OUT_];
        const float4 w1 = *(const float4*)&wp[(c4 * 4 + 1) * OUT_];
        const float4 w2 = *(const float4*)&wp[(c4 * 4 + 2) * OUT_];
        const float4 w3 = *(const float4*)&wp[(c4 * 4 + 3) * OUT_];
        #pragma unroll
        for (int i = 0; i < 4; i++) {
            const float4 nv = *(const float4*)&node_s[g * 4 + i][c4 * 4];
            acc4[i].x += nv.x * w0.x + nv.y * w1.x + nv.z * w2.x + nv.w * w3.x;
            acc4[i].y += nv.x * w0.y + nv.y * w1.y + nv.z * w2.y + nv.w * w3.y;
            acc4[i].z += nv.x * w0.z + nv.y * w1.z + nv.z * w2.z + nv.w * w3.z;
            acc4[i].w += nv.x * w0.w + nv.y * w1.w + nv.z * w2.w + nv.w * w3.w;
        }
    }
    #pragma unroll
    for (int i = 0; i < 4; i++) {
        const long n = n0 + g * 4 + i;
        *(float4*)&out[n * OUT_ + j0] = acc4[i];
    }
}

extern "C" void kernel_launch(void* const* d_in, const int* in_sizes, int n_in,
                              void* d_out, int out_size, void* d_ws, size_t ws_size,
                              hipStream_t stream)
{
    const float* message      = (const float*)d_in[0];
    const float* edge_attr    = (const float*)d_in[1];
    const float* edge_scalars = (const float*)d_in[2];
    const float* w_rad1       = (const float*)d_in[3];
    const float* b_rad1       = (const float*)d_in[4];
    const float* w_rad2       = (const float*)d_in[5];
    const float* b_rad2       = (const float*)d_in[6];
    const float* w_dtp_v      = (const float*)d_in[7];
    const float* w_lin_act    = (const float*)d_in[8];
    const float* b_lin_act    = (const float*)d_in[9];
    const float* w_alpha      = (const float*)d_in[10];
    const float* b_alpha      = (const float*)d_in[11];
    const float* w_lin_v      = (const float*)d_in[12];
    const float* b_lin_v      = (const float*)d_in[13];
    const float* alpha_dot    = (const float*)d_in[14];
    const float* w_proj       = (const float*)d_in[15];
    const float* b_proj       = (const float*)d_in[16];
    const int*   edge_dst     = (const int*)d_in[17];

    const int E = in_sizes[0] / C_;
    const int N = out_size / OUT_;

    // ws layout (zeroed region first):
    // [node N*256 f32][amax N*8 u32][denom N*8 f32][deg N i32] |
    // [base N][cursor N][sorted E][w_rad2_lin 32768s][w_alpha_lin 32768s]
    // [w_lin_act_lin 16384s][w_lin_v_lin 32768s][msg_bf E*128 s][logits E*8 f32]
    char* ws = (char*)d_ws;
    float*    node     = (float*)ws;
    unsigned* amax_u   = (unsigned*)(node + (size_t)N * AH_);
    float*    denom    = (float*)(amax_u + (size_t)N * H_);
    int*      deg      = (int*)(denom + (size_t)N * H_);
    int*      base     = deg + N;
    int*      cursor   = base + N;
    int*      sorted   = cursor + N;
    short*    w_rad2_l = (short*)(sorted + E);
    short*    w_alph_l = w_rad2_l + 64 * 512;
    short*    w_lact_l = w_alph_l + 128 * 256;
    short*    w_linv_l = w_lact_l + 128 * 128;
    short*    msg_bf   = w_linv_l + 128 * 256;
    float*    logits   = (float*)(msg_bf + (size_t)E * C_);

    hipMemsetAsync(d_ws, 0, (size_t)N * (AH_ + 2 * H_ + 1) * 4, stream);

    const int nbE256 = (E + 255) / 256;
    k_pack_dtp<<<64, 64, 0, stream>>>(w_rad2, w_rad2_l);
    k_pack<<<(256/16)*(128/32), 64, 0, stream>>>(w_alpha,   w_alph_l, 128, 256);
    k_pack<<<(128/16)*(128/32), 64, 0, stream>>>(w_lin_act, w_lact_l, 128, 128);
    k_pack<<<(256/16)*(128/32), 64, 0, stream>>>(w_lin_v,   w_linv_l, 128, 256);
    k_hist<<<nbE256, 256, 0, stream>>>(edge_dst, deg, E);
    k_scan<<<1, 1024, 0, stream>>>(deg, base, cursor, N);
    k_fill<<<nbE256, 256, 0, stream>>>(edge_dst, cursor, sorted, E);
    k_msgalpha<<<E / 64, 512, 0, stream>>>(message, edge_attr, edge_scalars,
                                           w_rad1, b_rad1, w_rad2_l, b_rad2,
                                           w_alph_l, b_alpha, alpha_dot, edge_dst,
                                           msg_bf, logits, amax_u);
    k_denom<<<(E * H_ + 255) / 256, 256, 0, stream>>>(logits, edge_dst, amax_u, denom, E * H_);
    k_value<<<E / 32, 256, 0, stream>>>(msg_bf, edge_attr, w_lact_l, b_lin_act, w_dtp_v,
                                        w_linv_l, b_lin_v, logits, edge_dst, amax_u, denom,
                                        sorted, node);
    k_proj<<<N / 32, 256, 0, stream>>>(node, w_proj, b_proj, (float*)d_out);
}

// Round 5
// 420.142 us; speedup vs baseline: 5.1419x; 1.0089x over previous
//
#include <hip/hip_runtime.h>
#include <hip/hip_bf16.h>

#define C_   128
#define A_   4
#define S_   16
#define RH_  64
#define H_   8
#define AH_  256
#define OUT_ 128

typedef __attribute__((ext_vector_type(8))) short bf16x8;
typedef __attribute__((ext_vector_type(4))) float f32x4;

__device__ __forceinline__ float sigf(float x) { return 1.0f / (1.0f + __expf(-x)); }

__device__ __forceinline__ unsigned short f2bf(float x) {
    unsigned u = __float_as_uint(x);
    unsigned r = (u + 0x7fffu + ((u >> 16) & 1u)) >> 16;   // RNE
    return (unsigned short)r;
}

// packed pair f32->bf16 (compiler emits v_cvt_pk_bf16_f32)
__device__ __forceinline__ unsigned pkbf(float a, float b) {
    union { __hip_bfloat162 h; unsigned u; } c;
    c.h = __float22bfloat162_rn(float2{a, b});
    return c.u;
}

// monotone float <-> uint mapping for atomicMax-based segment max
__device__ __forceinline__ unsigned enc(float x) {
    unsigned b = __float_as_uint(x);
    return (b & 0x80000000u) ? ~b : (b | 0x80000000u);
}
__device__ __forceinline__ float dec(unsigned u) {
    unsigned b = (u & 0x80000000u) ? (u & 0x7fffffffu) : ~u;
    return __uint_as_float(b);
}

// Pack f32 weight W[K][N] into bf16 fragment-linear layout for mfma_f32_16x16x32_bf16:
// out[((ct*(K/32)+ks)*64 + l)*8 + j] = W[ks*32 + (l>>4)*8 + j][ct*16 + (l&15)]
__global__ void k_pack(const float* __restrict__ W, short* __restrict__ out, int K, int N) {
    const int KS = K / 32;
    const int ct = blockIdx.x / KS, ks = blockIdx.x % KS;
    const int l = threadIdx.x, lr = l & 15, lg = l >> 4;
    bf16x8 v;
    #pragma unroll
    for (int j = 0; j < 8; j++)
        v[j] = (short)f2bf(W[(size_t)(ks * 32 + lg * 8 + j) * N + ct * 16 + lr]);
    *(bf16x8*)&out[((size_t)blockIdx.x * 64 + l) * 8] = v;
}

// Pack w_rad2 [64][512] as B'[k][c] with k = r*4+a (K=256), c in [0,128):
// B'[k][c] = w_rad2[k>>2][c*4 + (k&3)]
__global__ void k_pack_dtp(const float* __restrict__ W, short* __restrict__ out) {
    const int ct = blockIdx.x >> 3, ks = blockIdx.x & 7;
    const int l = threadIdx.x, lr = l & 15, lg = l >> 4;
    bf16x8 v;
    #pragma unroll
    for (int j = 0; j < 8; j++)
        v[j] = (short)f2bf(W[(size_t)(ks * 8 + lg * 2 + (j >> 2)) * 512 + (ct * 16 + lr) * 4 + (j & 3)]);
    *(bf16x8*)&out[((size_t)blockIdx.x * 64 + l) * 8] = v;
}

// CSR build: histogram, scan, fill
__global__ __launch_bounds__(256) void k_hist(
    const int* __restrict__ edge_dst, int* __restrict__ deg, int E)
{
    const int e = blockIdx.x * 256 + threadIdx.x;
    if (e < E) atomicAdd(&deg[edge_dst[e]], 1);
}

__global__ __launch_bounds__(1024) void k_scan(
    const int* __restrict__ deg, int* __restrict__ base, int* __restrict__ cursor, int N)
{
    __shared__ int part[1024];
    const int t = threadIdx.x;
    const int per = (N + 1023) / 1024;
    const int i0 = t * per;
    int s = 0;
    for (int i = 0; i < per; i++) { int idx = i0 + i; if (idx < N) s += deg[idx]; }
    part[t] = s;
    __syncthreads();
    for (int off = 1; off < 1024; off <<= 1) {
        int v = (t >= off) ? part[t - off] : 0;
        __syncthreads();
        part[t] += v;
        __syncthreads();
    }
    int excl = (t == 0) ? 0 : part[t - 1];
    for (int i = 0; i < per; i++) {
        int idx = i0 + i;
        if (idx < N) { base[idx] = excl; cursor[idx] = excl; excl += deg[idx]; }
    }
}

__global__ __launch_bounds__(256) void k_fill(
    const int* __restrict__ edge_dst, int* __restrict__ cursor,
    int* __restrict__ sorted, int E)
{
    const int e = blockIdx.x * 256 + threadIdx.x;
    if (e < E) {
        const int pos = atomicAdd(&cursor[edge_dst[e]], 1);
        sorted[pos] = e;
    }
}

// Fused msg + alpha. 64 edges/block, 512 threads (8 waves).
__global__ __launch_bounds__(512, 4) void k_msgalpha(
    const float* __restrict__ message, const float* __restrict__ edge_attr,
    const float* __restrict__ edge_scalars,
    const float* __restrict__ w_rad1, const float* __restrict__ b_rad1,
    const short* __restrict__ w_rad2_lin, const float* __restrict__ b_rad2,
    const short* __restrict__ w_alpha_lin, const float* __restrict__ b_alpha,
    const float* __restrict__ alpha_dot, const int* __restrict__ edge_dst,
    short* __restrict__ msg_bf, float* __restrict__ logits, unsigned* __restrict__ amax_u)
{
    __shared__ __align__(16) char smem[50432];
    short* Ap     = (short*)smem;                       // A' row stride 512B
    short* msg_s  = (short*)(smem + 32768);             // row stride 256B
    float* w1_s   = (float*)(smem + 32768);             // [16][64] overlay
    float* es_s   = (float*)(smem + 32768 + 4096);      // [64][17] overlay
    float* attr_s = (float*)(smem + 49152);             // [64][4]
    int*   dst_s  = (int*)(smem + 50176);               // [64]

    const int t = threadIdx.x;
    const long e0 = (long)blockIdx.x * 64;

    if (t < 256) {
        *(float4*)&w1_s[t * 4] = *(const float4*)&w_rad1[t * 4];
    } else {
        const int i = t - 256, r = i >> 2, s4 = (i & 3) * 4;
        *(float4*)&es_s[r * 17 + s4] = *(const float4*)&edge_scalars[(e0 + r) * S_ + s4];
    }
    if (t < 64) {
        *(float4*)&attr_s[t * 4] = *(const float4*)&edge_attr[(e0 + t) * A_];
        dst_s[t] = edge_dst[e0 + t];
    }
    __syncthreads();

    {   // Phase A: h = silu(es @ w_rad1 + b1); A'[r, 4c+a] = h[r,c]*attr[r,a]
        const int r = t & 63, o0 = (t >> 6) * 8;
        float acc[8];
        #pragma unroll
        for (int i = 0; i < 8; i++) acc[i] = b_rad1[o0 + i];
        #pragma unroll
        for (int s = 0; s < S_; s++) {
            const float ev = es_s[r * 17 + s];
            #pragma unroll
            for (int i = 0; i < 8; i++) acc[i] += ev * w1_s[s * 64 + o0 + i];
        }
        float h[8];
        #pragma unroll
        for (int i = 0; i < 8; i++) { const float x = acc[i]; h[i] = x * sigf(x); }
        const float4 a4 = *(const float4*)&attr_s[r * 4];
        char* base = (char*)Ap + r * 512;
        const int sw = (r & 31) << 4;
        #pragma unroll
        for (int c = 0; c < 4; c++) {
            const float h0 = h[2 * c], h1 = h[2 * c + 1];
            uint4 v;
            v.x = pkbf(h0 * a4.x, h0 * a4.y);
            v.y = pkbf(h0 * a4.z, h0 * a4.w);
            v.z = pkbf(h1 * a4.x, h1 * a4.y);
            v.w = pkbf(h1 * a4.z, h1 * a4.w);
            *(uint4*)(base + ((o0 * 8 + c * 16) ^ sw)) = v;
        }
    }
    __syncthreads();

    const int w = t >> 6, l = t & 63, lr = l & 15, lg = l >> 4;

    {   // Phase B: tp = A' @ B' + attr.b_rad2; msg = message * tp
        bf16x8 bf[8];
        #pragma unroll
        for (int ks = 0; ks < 8; ks++)
            bf[ks] = *(const bf16x8*)&w_rad2_lin[((size_t)(w * 8 + ks) * 64 + l) * 8];
        const int col = w * 16 + lr;
        const float4 b2 = *(const float4*)&b_rad2[col * 4];
        #pragma unroll 1
        for (int rt = 0; rt < 4; rt++) {
            const int arow = rt * 16 + lr;
            const char* abase = (char*)Ap + arow * 512;
            const int asw = (arow & 31) << 4;
            bf16x8 af[8];
            #pragma unroll
            for (int ks = 0; ks < 8; ks++)
                af[ks] = *(const bf16x8*)(abase + ((ks * 64 + lg * 16) ^ asw));
            f32x4 acc = {0.f, 0.f, 0.f, 0.f};
            #pragma unroll
            for (int ks = 0; ks < 8; ks++)
                acc = __builtin_amdgcn_mfma_f32_16x16x32_bf16(af[ks], bf[ks], acc, 0, 0, 0);
            #pragma unroll
            for (int r = 0; r < 4; r++) {
                const int row = rt * 16 + lg * 4 + r;
                const float4 a4 = *(const float4*)&attr_s[row * 4];
                const float badj = a4.x * b2.x + a4.y * b2.y + a4.z * b2.z + a4.w * b2.w;
                const float m = message[(e0 + row) * C_ + col];
                *(short*)((char*)msg_s + row * 256 + ((col * 2) ^ ((row & 15) << 4))) =
                    (short)f2bf(m * (acc[r] + badj));
            }
        }
    }
    __syncthreads();

    {   // Phase C: msg_s -> global (linear bf16 rows)
        #pragma unroll
        for (int i = 0; i < 2; i++) {
            const int q = t + i * 512;
            const int row = q >> 4, ch = q & 15;
            const uint4 v = *(const uint4*)((char*)msg_s + row * 256 + ((ch * 16) ^ ((row & 15) << 4)));
            *(uint4*)((char*)msg_bf + ((e0 + row) * 256 + ch * 16)) = v;
        }
    }

    {   // Phase D: wave w computes head w for all 64 edges (transposed GEMM)
        bf16x8 waf[2][4];
        float4 ba4[2], ad4[2];
        #pragma unroll
        for (int q = 0; q < 2; q++) {
            const int rt = w * 2 + q;
            #pragma unroll
            for (int ks = 0; ks < 4; ks++)
                waf[q][ks] = *(const bf16x8*)&w_alpha_lin[((size_t)(rt * 4 + ks) * 64 + l) * 8];
            ba4[q] = *(const float4*)&b_alpha[rt * 16 + lg * 4];
            ad4[q] = *(const float4*)&alpha_dot[rt * 16 + lg * 4];
        }
        #pragma unroll 1
        for (int ct = 0; ct < 4; ct++) {
            const int erow = ct * 16 + lr;
            const char* mbase = (char*)msg_s + erow * 256;
            const int msw = (erow & 15) << 4;
            bf16x8 mb[4];
            #pragma unroll
            for (int ks = 0; ks < 4; ks++)
                mb[ks] = *(const bf16x8*)(mbase + ((ks * 64 + lg * 16) ^ msw));
            float s = 0.f;
            #pragma unroll
            for (int q = 0; q < 2; q++) {
                f32x4 acc = {0.f, 0.f, 0.f, 0.f};
                #pragma unroll
                for (int ks = 0; ks < 4; ks++)
                    acc = __builtin_amdgcn_mfma_f32_16x16x32_bf16(waf[q][ks], mb[ks], acc, 0, 0, 0);
                #pragma unroll
                for (int r = 0; r < 4; r++) {
                    const float x = acc[r] + ((const float*)&ba4[q])[r];
                    const float y = x * (0.2f + 0.8f * sigf(x));   // SmoothLeakyReLU, a=0.2
                    s += y * ((const float*)&ad4[q])[r];
                }
            }
            s += __shfl_xor(s, 16);
            s += __shfl_xor(s, 32);
            if (lg == 0) {
                const long e = e0 + ct * 16 + lr;
                logits[e * H_ + w] = s;
                atomicMax(&amax_u[dst_s[ct * 16 + lr] * H_ + w], enc(s));
            }
        }
    }
}

// K3: denom[n,h] += exp(logit - amax)
__global__ __launch_bounds__(256) void k_denom(
    const float* __restrict__ logits, const int* __restrict__ edge_dst,
    const unsigned* __restrict__ amax_u, float* __restrict__ denom, int EH)
{
    const int t = blockIdx.x * 256 + threadIdx.x;
    if (t >= EH) return;
    const int e = t >> 3, h = t & 7;
    const int n = edge_dst[e];
    const float am = dec(amax_u[n * H_ + h]);
    atomicAdd(&denom[n * H_ + h], __expf(logits[t] - am));
}

// K4: dst-sorted edges, 64 per block, 512 threads (8 waves). MFMA gate + value
// GEMMs; val2 (f32, stride 260) overlays the staging LDS; run-length reduce by
// dst in two 32-edge halves (interior: plain store, boundary: atomicAdd).
__global__ __launch_bounds__(512, 2) void k_value(
    const short* __restrict__ msg_bf, const float* __restrict__ edge_attr,
    const short* __restrict__ w_lin_act_lin, const float* __restrict__ b_lin_act,
    const float* __restrict__ w_dtp_v,
    const short* __restrict__ w_lin_v_lin, const float* __restrict__ b_lin_v,
    const float* __restrict__ logits, const int* __restrict__ edge_dst,
    const unsigned* __restrict__ amax_u, const float* __restrict__ denom,
    const int* __restrict__ sorted, float* __restrict__ node)
{
    __shared__ __align__(16) char pool[66560];   // val2 [64][260] f32 overlays a_s/v_s
    __shared__ float attr_s[64][4];
    __shared__ float wgt_s[64][H_];
    __shared__ int   dst_s[64];
    __shared__ int   eid_s[64];
    short* a_s  = (short*)pool;            // [64] rows x 256B, swizzled
    short* v_s  = (short*)(pool + 16384);  // [64] rows x 256B, swizzled
    float* val2 = (float*)pool;

    const int t = threadIdx.x;
    const int b0 = blockIdx.x * 64;

    if (t < 64) {
        const int e = sorted[b0 + t];
        eid_s[t] = e;
        dst_s[t] = edge_dst[e];
        *(float4*)&attr_s[t][0] = *(const float4*)&edge_attr[(long)e * A_];
    }
    __syncthreads();
    #pragma unroll
    for (int i = 0; i < 2; i++) {   // gather msg rows -> swizzled LDS
        const int q = t + i * 512;
        const int row = q >> 4, ch = q & 15;
        const uint4 v = *(const uint4*)((const char*)msg_bf + ((long)eid_s[row] * 256 + ch * 16));
        *(uint4*)((char*)a_s + row * 256 + ((ch * 16) ^ ((row & 15) << 4))) = v;
    }
    {   // softmax weights, one (el,h) per thread
        const int el = t >> 3, h = t & 7;
        const long e = eid_s[el];
        const int n = dst_s[el];
        const float am = dec(amax_u[n * H_ + h]);
        const float d  = denom[n * H_ + h];
        wgt_s[el][h] = __expf(logits[e * H_ + h] - am) / (d + 1e-16f);
    }
    __syncthreads();

    const int w = t >> 6, l = t & 63, lr = l & 15, lg = l >> 4;
    {   // gate GEMM: wave w owns col-tile w (16 cols), all 64 rows
        bf16x8 af[4][4];
        #pragma unroll
        for (int rt = 0; rt < 4; rt++)
            #pragma unroll
            for (int ks = 0; ks < 4; ks++) {
                const int row = rt * 16 + lr;
                af[rt][ks] = *(bf16x8*)((char*)a_s + row * 256 + ((ks * 64 + lg * 16) ^ ((row & 15) << 4)));
            }
        bf16x8 bf[4];
        #pragma unroll
        for (int ks = 0; ks < 4; ks++)
            bf[ks] = *(const bf16x8*)&w_lin_act_lin[((size_t)(w * 4 + ks) * 64 + l) * 8];
        const int col = w * 16 + lr;
        const float bb = b_lin_act[col];
        const float4 wv = *(const float4*)&w_dtp_v[col * 4];
        #pragma unroll
        for (int rt = 0; rt < 4; rt++) {
            f32x4 acc = {0.f, 0.f, 0.f, 0.f};
            #pragma unroll
            for (int ks = 0; ks < 4; ks++)
                acc = __builtin_amdgcn_mfma_f32_16x16x32_bf16(af[rt][ks], bf[ks], acc, 0, 0, 0);
            #pragma unroll
            for (int r = 0; r < 4; r++) {
                const int row = rt * 16 + lg * 4 + r;
                float x = acc[r] + bb;
                x = x * sigf(x);
                const float4 a4 = *(const float4*)&attr_s[row][0];
                const float dv = wv.x * a4.x + wv.y * a4.y + wv.z * a4.z + wv.w * a4.w;
                *(short*)((char*)v_s + row * 256 + ((col * 2) ^ ((row & 15) << 4))) =
                    (short)f2bf(x * dv);
            }
        }
    }
    __syncthreads();

    bf16x8 vf[4][4];
    #pragma unroll
    for (int rt = 0; rt < 4; rt++)
        #pragma unroll
        for (int ks = 0; ks < 4; ks++) {
            const int row = rt * 16 + lr;
            vf[rt][ks] = *(bf16x8*)((char*)v_s + row * 256 + ((ks * 64 + lg * 16) ^ ((row & 15) << 4)));
        }
    __syncthreads();   // all v_s reads done; pool can be overwritten by val2

    #pragma unroll
    for (int q = 0; q < 2; q++) {   // value GEMM: wave w owns col-tiles w*2, w*2+1
        const int ct = w * 2 + q;
        bf16x8 bf[4];
        #pragma unroll
        for (int ks = 0; ks < 4; ks++)
            bf[ks] = *(const bf16x8*)&w_lin_v_lin[((size_t)(ct * 4 + ks) * 64 + l) * 8];
        const int col = ct * 16 + lr;
        const float bb = b_lin_v[col];
        #pragma unroll
        for (int rt = 0; rt < 4; rt++) {
            f32x4 acc = {0.f, 0.f, 0.f, 0.f};
            #pragma unroll
            for (int ks = 0; ks < 4; ks++)
                acc = __builtin_amdgcn_mfma_f32_16x16x32_bf16(vf[rt][ks], bf[ks], acc, 0, 0, 0);
            #pragma unroll
            for (int r = 0; r < 4; r++) {
                const int row = rt * 16 + lg * 4 + r;
                val2[row * 260 + col] = (acc[r] + bb) * wgt_s[row][col >> 5];
            }
        }
    }
    __syncthreads();
    {   // run-length reduce by dst; thread owns channel c over a 32-edge half
        const int c = t & 255, eS = (t >> 8) * 32, eE = eS + 32;
        float run = 0.f;
        int s = eS;
        #pragma unroll 1
        for (int e = eS; e < eE; e++) {
            run += val2[e * 260 + c];
            const bool end = (e == eE - 1) || (dst_s[e + 1] != dst_s[e]);
            if (end) {
                float* np = node + (long)dst_s[e] * AH_ + c;
                if (s == eS || e == eE - 1) atomicAdd(np, run);
                else *np = run;
                run = 0.f; s = e + 1;
            }
        }
    }
}

// K5: out = node @ w_proj + b_proj
__global__ __launch_bounds__(256) void k_proj(
    const float* __restrict__ node, const float* __restrict__ w_proj,
    const float* __restrict__ b_proj, float* __restrict__ out)
{
    __shared__ float node_s[32][AH_];   // 32KB
    const int t = threadIdx.x;
    const long n0 = (long)blockIdx.x * 32;
    #pragma unroll
    for (int i = 0; i < 8; i++) {
        const int idx = t + i * 256;
        const int nl = idx >> 6, c4 = (idx & 63) * 4;
        *(float4*)&node_s[nl][c4] = *(const float4*)&node[(n0 + nl) * AH_ + c4];
    }
    __syncthreads();
    const int j0 = (t & 31) * 4;
    const int g  = t >> 5;
    float4 acc4[4];
    const float4 b = *(const float4*)&b_proj[j0];
    #pragma unroll
    for (int i = 0; i < 4; i++) acc4[i] = b;
    const float* wp = w_proj + j0;
    for (int c4 = 0; c4 < 64; c4++) {
        const float4 w0 = *(const float4*)&wp[(c4 * 4 + 0) * OUT_];
        const float4 w1 = *(const float4*)&wp[(c4 * 4 + 1) * OUT_];
        const float4 w2 = *(const float4*)&wp[(c4 * 4 + 2) * OUT_];
        const float4 w3 = *(const float4*)&wp[(c4 * 4 + 3) * OUT_];
        #pragma unroll
        for (int i = 0; i < 4; i++) {
            const float4 nv = *(const float4*)&node_s[g * 4 + i][c4 * 4];
            acc4[i].x += nv.x * w0.x + nv.y * w1.x + nv.z * w2.x + nv.w * w3.x;
            acc4[i].y += nv.x * w0.y + nv.y * w1.y + nv.z * w2.y + nv.w * w3.y;
            acc4[i].z += nv.x * w0.z + nv.y * w1.z + nv.z * w2.z + nv.w * w3.z;
            acc4[i].w += nv.x * w0.w + nv.y * w1.w + nv.z * w2.w + nv.w * w3.w;
        }
    }
    #pragma unroll
    for (int i = 0; i < 4; i++) {
        const long n = n0 + g * 4 + i;
        *(float4*)&out[n * OUT_ + j0] = acc4[i];
    }
}

extern "C" void kernel_launch(void* const* d_in, const int* in_sizes, int n_in,
                              void* d_out, int out_size, void* d_ws, size_t ws_size,
                              hipStream_t stream)
{
    const float* message      = (const float*)d_in[0];
    const float* edge_attr    = (const float*)d_in[1];
    const float* edge_scalars = (const float*)d_in[2];
    const float* w_rad1       = (const float*)d_in[3];
    const float* b_rad1       = (const float*)d_in[4];
    const float* w_rad2       = (const float*)d_in[5];
    const float* b_rad2       = (const float*)d_in[6];
    const float* w_dtp_v      = (const float*)d_in[7];
    const float* w_lin_act    = (const float*)d_in[8];
    const float* b_lin_act    = (const float*)d_in[9];
    const float* w_alpha      = (const float*)d_in[10];
    const float* b_alpha      = (const float*)d_in[11];
    const float* w_lin_v      = (const float*)d_in[12];
    const float* b_lin_v      = (const float*)d_in[13];
    const float* alpha_dot    = (const float*)d_in[14];
    const float* w_proj       = (const float*)d_in[15];
    const float* b_proj       = (const float*)d_in[16];
    const int*   edge_dst     = (const int*)d_in[17];

    const int E = in_sizes[0] / C_;
    const int N = out_size / OUT_;

    // ws layout (zeroed region first):
    // [node N*256 f32][amax N*8 u32][denom N*8 f32][deg N i32] |
    // [base N][cursor N][sorted E][w_rad2_lin][w_alpha_lin][w_lin_act_lin]
    // [w_lin_v_lin][msg_bf E*128 s][logits E*8 f32]
    char* ws = (char*)d_ws;
    float*    node     = (float*)ws;
    unsigned* amax_u   = (unsigned*)(node + (size_t)N * AH_);
    float*    denom    = (float*)(amax_u + (size_t)N * H_);
    int*      deg      = (int*)(denom + (size_t)N * H_);
    int*      base     = deg + N;
    int*      cursor   = base + N;
    int*      sorted   = cursor + N;
    short*    w_rad2_l = (short*)(sorted + E);
    short*    w_alph_l = w_rad2_l + 64 * 512;
    short*    w_lact_l = w_alph_l + 128 * 256;
    short*    w_linv_l = w_lact_l + 128 * 128;
    short*    msg_bf   = w_linv_l + 128 * 256;
    float*    logits   = (float*)(msg_bf + (size_t)E * C_);

    hipMemsetAsync(d_ws, 0, (size_t)N * (AH_ + 2 * H_ + 1) * 4, stream);

    const int nbE256 = (E + 255) / 256;
    k_pack_dtp<<<64, 64, 0, stream>>>(w_rad2, w_rad2_l);
    k_pack<<<(256/16)*(128/32), 64, 0, stream>>>(w_alpha,   w_alph_l, 128, 256);
    k_pack<<<(128/16)*(128/32), 64, 0, stream>>>(w_lin_act, w_lact_l, 128, 128);
    k_pack<<<(256/16)*(128/32), 64, 0, stream>>>(w_lin_v,   w_linv_l, 128, 256);
    k_hist<<<nbE256, 256, 0, stream>>>(edge_dst, deg, E);
    k_scan<<<1, 1024, 0, stream>>>(deg, base, cursor, N);
    k_fill<<<nbE256, 256, 0, stream>>>(edge_dst, cursor, sorted, E);
    k_msgalpha<<<E / 64, 512, 0, stream>>>(message, edge_attr, edge_scalars,
                                           w_rad1, b_rad1, w_rad2_l, b_rad2,
                                           w_alph_l, b_alpha, alpha_dot, edge_dst,
                                           msg_bf, logits, amax_u);
    k_denom<<<(E * H_ + 255) / 256, 256, 0, stream>>>(logits, edge_dst, amax_u, denom, E * H_);
    k_value<<<E / 64, 512, 0, stream>>>(msg_bf, edge_attr, w_lact_l, b_lin_act, w_dtp_v,
                                        w_linv_l, b_lin_v, logits, edge_dst, amax_u, denom,
                                        sorted, node);
    k_proj<<<N / 32, 256, 0, stream>>>(node, w_proj, b_proj, (float*)d_out);
}